// Round 8
// baseline (239.709 us; speedup 1.0000x reference)
//
#include <hip/hip_runtime.h>
#include <hip/hip_bf16.h>
#include <hip/hip_fp16.h>

#define N_NODES 50000
#define N_EDGES 800000
#define NTILES 3125        // N_NODES / 16
#define W_TOTAL 57344      // packed bf16 weight elements (W1 slot unused)
#define WB2 192            // pack blocks (W2..A4b = 49152 elems)
#define TB 782             // layer1/dense MFMA blocks (4 waves each)
#define ROWCAP 64          // padded-CSR slots per node (deg mean 16, 12-sigma safe)
#define ZROW N_NODES       // index of the all-zero fp8 row used for slot padding

#define NBKT 200           // dst-range buckets
#define BKT_NODES 250      // nodes per bucket (200*250 = 50000)
#define BKT_CAP 4400       // edges per bucket capacity (mean 4000, +6.3 sigma)
#define ABLK 256           // bin blocks (phase A)
#define ACH ((N_EDGES + ABLK - 1) / ABLK)   // 3125 edges per bin block

typedef __attribute__((ext_vector_type(8))) short bf16x8;          // MFMA A/B frag
typedef __attribute__((ext_vector_type(4))) float f32x4;           // MFMA C/D frag
typedef __attribute__((ext_vector_type(2))) float f32x2;           // packed f32 pair
typedef __attribute__((ext_vector_type(8))) unsigned short u16x8;  // 16B load/store
typedef __attribute__((ext_vector_type(4))) unsigned int u32x4;    // 16B load (ext-vec for nt builtins)

__device__ inline unsigned short f2bf(float f) {  // round-to-nearest-even
    unsigned int x = __float_as_uint(f);
    unsigned int r = (x + 0x7FFF + ((x >> 16) & 1)) >> 16;
    return (unsigned short)r;
}
__device__ inline float2 h2f2(unsigned int u) {   // packed half2 -> float2
    __half2 h = *(__half2*)&u;
    return make_float2(__low2float(h), __high2float(h));
}
__device__ inline unsigned int f22h2(float a, float b) {  // 2 floats -> packed half2
    __half2 h = __floats2half2_rn(a, b);
    return *(unsigned int*)&h;
}

// ---------------------------------------------------------------------------
// PASS A (one launch, three independent block roles):
//  [0, ABLK)        : edge BINNING by dst-range (LDS histogram + one global
//                     atomic per (block,bucket), packed (dl<<16|src) run writes).
//  [ABLK, +TB)      : layer1 MFMA -> UNSCALED h (fp16) in Ht.
//  [ABLK+TB, end)   : bf16-pack W2..A4b into wpAll[8192..].
__global__ __launch_bounds__(256) void passA_kernel(
    const float* __restrict__ x, const int* __restrict__ src, const int* __restrict__ dst,
    const float* __restrict__ W1, const float* __restrict__ b1,
    const float* W2, const float* A2a, const float* A2b,
    const float* W3, const float* A3a, const float* A3b,
    const float* W4, const float* A4a, const float* A4b,
    int* __restrict__ bucketCnt, unsigned int* __restrict__ bktArr,
    unsigned short* __restrict__ wp, __half* __restrict__ Ht) {
    int tid = threadIdx.x;

    if (blockIdx.x < ABLK) {                      // ---- bin edges ----
        __shared__ int hist[NBKT];
        __shared__ int gbase[NBKT];
        __shared__ int hoff[NBKT];
        if (tid < NBKT) { hist[tid] = 0; hoff[tid] = 0; }
        __syncthreads();
        int e0 = blockIdx.x * ACH;
        int e1 = min(e0 + ACH, N_EDGES);
        for (int e = e0 + tid; e < e1; e += 256)
            atomicAdd(&hist[dst[e] / BKT_NODES], 1);
        __syncthreads();
        if (tid < NBKT) {
            int h = hist[tid];
            gbase[tid] = h ? atomicAdd(&bucketCnt[tid], h) : 0;
        }
        __syncthreads();
        for (int e = e0 + tid; e < e1; e += 256) {
            int d = dst[e];
            int b = d / BKT_NODES;
            int pos = gbase[b] + atomicAdd(&hoff[b], 1);
            if (pos < BKT_CAP)
                bktArr[(size_t)b * BKT_CAP + pos] =
                    ((unsigned int)(d - b * BKT_NODES) << 16) | (unsigned int)src[e];
        }
        return;
    }
    if (blockIdx.x >= ABLK + TB) {                // ---- pack W2..A4b ----
        int i = 8192 + (blockIdx.x - ABLK - TB) * 256 + tid;
        if (i >= W_TOTAL) return;
        float v;
        if (i < 16384)      v = W2[i - 8192];
        else if (i < 20480) v = A2a[i - 16384];
        else if (i < 24576) v = A2b[i - 20480];
        else if (i < 32768) v = W3[i - 24576];
        else if (i < 36864) v = A3a[i - 32768];
        else if (i < 40960) v = A3b[i - 36864];
        else if (i < 49152) v = W4[i - 40960];
        else if (i < 53248) v = A4a[i - 49152];
        else                v = A4b[i - 53248];
        wp[i] = f2bf(v);
        return;
    }

    // ---- layer1: h = relu(x @ W1^T + b1) -> Ht (fp16, unscaled) ----
    int wave = ((blockIdx.x - ABLK) * 256 + tid) >> 6;
    if (wave >= NTILES) return;
    int lane = tid & 63;
    int r16 = lane & 15, quad = lane >> 4;
    int base = wave * 16;

    bf16x8 a[4];
    const float* xr = x + (size_t)(base + r16) * 128 + quad * 8;
#pragma unroll
    for (int kb = 0; kb < 4; kb++) {
        float4 f0 = *(const float4*)(xr + kb * 32);
        float4 f1 = *(const float4*)(xr + kb * 32 + 4);
        bf16x8 v;
        v[0] = (short)f2bf(f0.x); v[1] = (short)f2bf(f0.y);
        v[2] = (short)f2bf(f0.z); v[3] = (short)f2bf(f0.w);
        v[4] = (short)f2bf(f1.x); v[5] = (short)f2bf(f1.y);
        v[6] = (short)f2bf(f1.z); v[7] = (short)f2bf(f1.w);
        a[kb] = v;
    }

#pragma unroll
    for (int jt = 0; jt < 4; jt++) {
        f32x4 acc = {0.f, 0.f, 0.f, 0.f};
        const float* wr = W1 + (size_t)(jt * 16 + r16) * 128 + quad * 8;
#pragma unroll
        for (int kb = 0; kb < 4; kb++) {
            float4 g0 = *(const float4*)(wr + kb * 32);
            float4 g1 = *(const float4*)(wr + kb * 32 + 4);
            bf16x8 b;
            b[0] = (short)f2bf(g0.x); b[1] = (short)f2bf(g0.y);
            b[2] = (short)f2bf(g0.z); b[3] = (short)f2bf(g0.w);
            b[4] = (short)f2bf(g1.x); b[5] = (short)f2bf(g1.y);
            b[6] = (short)f2bf(g1.z); b[7] = (short)f2bf(g1.w);
            acc = __builtin_amdgcn_mfma_f32_16x16x32_bf16(a[kb], b, acc, 0, 0, 0);
        }
        int col = jt * 16 + r16;
        float bias = b1[col];
#pragma unroll
        for (int r = 0; r < 4; r++) {
            int row = base + quad * 4 + r;
            float v = fmaxf(acc[r] + bias, 0.f);
            Ht[(size_t)row * 64 + col] = __float2half(v);
        }
    }
}

// ---------------------------------------------------------------------------
// PASS B (R7: csr + scale FUSED): one block per bucket.
//  1) slot assignment via LDS atomics; scattered 2B stores confined to the
//     bucket's 32 KB srcAp region (L2-resident).
//  2) ZROW padding + cnt/isq/sdeg from the LDS degrees.
//  3) scale its 250 rows: As = Ht*isq (fp16), As8 = fp8 e4m3 gather copy.
__global__ __launch_bounds__(256) void csr_scale_k(const int* __restrict__ bucketCnt,
                                                   const unsigned int* __restrict__ bktArr,
                                                   const __half* __restrict__ Ht,
                                                   unsigned short* __restrict__ srcAp,
                                                   int* __restrict__ cnt,
                                                   __half* __restrict__ As,
                                                   unsigned char* __restrict__ As8,
                                                   float* __restrict__ isq,
                                                   float* __restrict__ sdeg) {
    __shared__ int lcnt[BKT_NODES];
    int b = blockIdx.x, tid = threadIdx.x;
    if (tid < BKT_NODES) lcnt[tid] = 0;
    __syncthreads();
    int n = min(bucketCnt[b], BKT_CAP);
    int rowbase = b * BKT_NODES;
    const unsigned int* arr = bktArr + (size_t)b * BKT_CAP;
    for (int i = tid; i < n; i += 256) {
        unsigned int u = arr[i];
        int dl = (int)(u >> 16);
        int pos = atomicAdd(&lcnt[dl], 1);
        if (pos < ROWCAP)
            srcAp[(size_t)(rowbase + dl) * ROWCAP + pos] = (unsigned short)(u & 0xFFFF);
    }
    __syncthreads();
    if (tid < BKT_NODES) {
        int deg = lcnt[tid];
        int cv = min(deg, ROWCAP);
        int cvr = (cv + 7) & ~7;
        for (int j = cv; j < cvr; j++)
            srcAp[(size_t)(rowbase + tid) * ROWCAP + j] = (unsigned short)ZROW;
        cnt[rowbase + tid] = deg;
        float dv = fmaxf((float)deg, 1.0f);
        isq[rowbase + tid] = rsqrtf(dv);
        sdeg[rowbase + tid] = sqrtf(dv);
    }
    __syncthreads();
    // scale: 16 threads per row, 16 rows per sweep
    int sl = tid & 15;
    for (int rr = tid >> 4; rr < BKT_NODES; rr += 16) {
        int row = rowbase + rr;
        float is = rsqrtf(fmaxf((float)lcnt[rr], 1.0f));
        uint2 rv = *((const uint2*)(Ht + (size_t)row * 64) + sl);   // 4 halves
        float2 fa = h2f2(rv.x), fb = h2f2(rv.y);
        float s0 = fa.x * is, s1 = fa.y * is, s2 = fb.x * is, s3 = fb.y * is;
        uint2 ov;
        ov.x = f22h2(s0, s1);
        ov.y = f22h2(s2, s3);
        *((uint2*)(As + (size_t)row * 64) + sl) = ov;
        unsigned int w = __builtin_amdgcn_cvt_pk_fp8_f32(s0, s1, 0, false);
        w = __builtin_amdgcn_cvt_pk_fp8_f32(s2, s3, w, true);
        ((unsigned int*)As8)[(size_t)row * 16 + sl] = w;            // 4 fp8 bytes
    }
}

// ---------------------------------------------------------------------------
// FUSED conv + dense, one block = 64 rows (4 MFMA tiles, wave-independent).
// conv: 16 rows x 4 feat-lanes, 16B fp8 gathers; one wave instr = 16 edges.
// R7 MEASUREMENT PROBE: `reps` repeats the gather/accumulate loop; acc is
//   scaled by 1/reps (numerically ~identical). Layer 2 runs reps=2 so its
//   dispatch exceeds the 44us harness-fill cutoff and surfaces in rocprof
//   with its own FETCH -- decides L2-miss vs latency theory for the gather.
// dense: fp16 path; fp8 error enters ONLY through the conv half of concat.
__global__ __launch_bounds__(256) void conv_dense_k(const __half* __restrict__ hs,
                                                    const unsigned char* __restrict__ hs8,
                                                    const int* __restrict__ cnt,
                                                    const unsigned short* __restrict__ srcAp,
                                                    const float* __restrict__ isq,
                                                    const float* __restrict__ sdeg,
                                                    const unsigned short* __restrict__ wp,
                                                    const unsigned short* __restrict__ aap,
                                                    const unsigned short* __restrict__ abp,
                                                    __half* __restrict__ outs,
                                                    unsigned char* __restrict__ outs8,
                                                    float* __restrict__ outf,
                                                    int finalLayer, int reps) {
    __shared__ unsigned short clds[64][64];   // conv result (bf16), 8 KB
    int tid = threadIdx.x;
    int wv = tid >> 6;
    int lane = tid & 63;
    int t = blockIdx.x * 4 + wv;
    if (t >= NTILES) return;
    int base = t * 16;   // N_NODES % 16 == 0: all rows valid

    // ---- conv phase (no barrier: wave reads only its own clds quarter) ----
    {
        int r = lane >> 2, fl = lane & 3;      // 16 rows x 4 feat-lanes
        int row = base + r;
        int b = row * ROWCAP;
        int cv = min(cnt[row], ROWCAP);
        int cvr = (cv + 7) & ~7;               // slots [cv,cvr) = ZROW (zeros)
        f32x2 acc[8];
#pragma unroll
        for (int k = 0; k < 8; k++) acc[k] = (f32x2){0.f, 0.f};
        for (int rep = 0; rep < reps; rep++) {
            if (cvr) {
                u16x8 sv = __builtin_nontemporal_load((const u16x8*)(srcAp + b));
                for (int i = 0; i < cvr; i += 8) {
                    u16x8 svn = sv;                // prefetch next slot vector
                    if (i + 8 < cvr)
                        svn = __builtin_nontemporal_load((const u16x8*)(srcAp + b + i + 8));
                    u32x4 rv[8];
#pragma unroll
                    for (int u = 0; u < 8; u++)
                        rv[u] = *((const u32x4*)(hs8 + (size_t)(int)sv[u] * 64) + fl);
#pragma unroll
                    for (int u = 0; u < 8; u++) {
                        acc[0] += __builtin_amdgcn_cvt_pk_f32_fp8(rv[u][0], false);
                        acc[1] += __builtin_amdgcn_cvt_pk_f32_fp8(rv[u][0], true);
                        acc[2] += __builtin_amdgcn_cvt_pk_f32_fp8(rv[u][1], false);
                        acc[3] += __builtin_amdgcn_cvt_pk_f32_fp8(rv[u][1], true);
                        acc[4] += __builtin_amdgcn_cvt_pk_f32_fp8(rv[u][2], false);
                        acc[5] += __builtin_amdgcn_cvt_pk_f32_fp8(rv[u][2], true);
                        acc[6] += __builtin_amdgcn_cvt_pk_f32_fp8(rv[u][3], false);
                        acc[7] += __builtin_amdgcn_cvt_pk_f32_fp8(rv[u][3], true);
                    }
                    sv = svn;
                }
            }
        }
        float sc = isq[row] * (reps == 2 ? 0.5f : 1.0f);
        u16x8 o0, o1;
#pragma unroll
        for (int k = 0; k < 4; k++) {
            o0[2 * k]     = f2bf(acc[k][0] * sc);
            o0[2 * k + 1] = f2bf(acc[k][1] * sc);
            o1[2 * k]     = f2bf(acc[4 + k][0] * sc);
            o1[2 * k + 1] = f2bf(acc[4 + k][1] * sc);
        }
        // lane (r,fl) owns feats [fl*16, fl*16+16) of its row
        *(u16x8*)(&clds[wv * 16 + r][fl * 16]) = o0;
        *(u16x8*)(&clds[wv * 16 + r][fl * 16 + 8]) = o1;
    }

    // ---- dense phase ----
    int r16 = lane & 15, quad = lane >> 4;
    float rs = sdeg[base + r16];                 // h = hs * sqrt(deg), per A-row
    const u32x4* hp = (const u32x4*)(hs + (size_t)(base + r16) * 64);
    u32x4 raw0 = __builtin_nontemporal_load(hp + quad);      // feats quad*8 .. +8
    u32x4 raw1 = __builtin_nontemporal_load(hp + 4 + quad);  // feats 32+quad*8 .. +8
    bf16x8 ha0, ha1;
    {
        float2 f;
        f = h2f2(raw0[0]); ha0[0] = (short)f2bf(f.x * rs); ha0[1] = (short)f2bf(f.y * rs);
        f = h2f2(raw0[1]); ha0[2] = (short)f2bf(f.x * rs); ha0[3] = (short)f2bf(f.y * rs);
        f = h2f2(raw0[2]); ha0[4] = (short)f2bf(f.x * rs); ha0[5] = (short)f2bf(f.y * rs);
        f = h2f2(raw0[3]); ha0[6] = (short)f2bf(f.x * rs); ha0[7] = (short)f2bf(f.y * rs);
        f = h2f2(raw1[0]); ha1[0] = (short)f2bf(f.x * rs); ha1[1] = (short)f2bf(f.y * rs);
        f = h2f2(raw1[1]); ha1[2] = (short)f2bf(f.x * rs); ha1[3] = (short)f2bf(f.y * rs);
        f = h2f2(raw1[2]); ha1[4] = (short)f2bf(f.x * rs); ha1[5] = (short)f2bf(f.y * rs);
        f = h2f2(raw1[3]); ha1[6] = (short)f2bf(f.x * rs); ha1[7] = (short)f2bf(f.y * rs);
    }
    bf16x8 ca0 = *(const bf16x8*)(&clds[wv * 16 + r16][quad * 8]);
    bf16x8 ca1 = *(const bf16x8*)(&clds[wv * 16 + r16][32 + quad * 8]);

    float isq4[4];
    if (!finalLayer) {
#pragma unroll
        for (int r = 0; r < 4; r++) isq4[r] = isq[base + quad * 4 + r];
    }

#pragma unroll
    for (int jt = 0; jt < 4; jt++) {
        const unsigned short* wr = wp + (size_t)(jt * 16 + r16) * 128 + quad * 8;
        const unsigned short* ar = aap + (size_t)(jt * 16 + r16) * 64 + quad * 8;
        const unsigned short* br = abp + (size_t)(jt * 16 + r16) * 64 + quad * 8;
        f32x4 P = {0.f, 0.f, 0.f, 0.f};
        f32x4 Q = {0.f, 0.f, 0.f, 0.f};
        f32x4 R = {0.f, 0.f, 0.f, 0.f};
        P = __builtin_amdgcn_mfma_f32_16x16x32_bf16(ha0, *(const bf16x8*)(wr), P, 0, 0, 0);
        P = __builtin_amdgcn_mfma_f32_16x16x32_bf16(ha1, *(const bf16x8*)(wr + 32), P, 0, 0, 0);
        P = __builtin_amdgcn_mfma_f32_16x16x32_bf16(ca0, *(const bf16x8*)(wr + 64), P, 0, 0, 0);
        P = __builtin_amdgcn_mfma_f32_16x16x32_bf16(ca1, *(const bf16x8*)(wr + 96), P, 0, 0, 0);
        Q = __builtin_amdgcn_mfma_f32_16x16x32_bf16(ha0, *(const bf16x8*)(ar), Q, 0, 0, 0);
        Q = __builtin_amdgcn_mfma_f32_16x16x32_bf16(ha1, *(const bf16x8*)(ar + 32), Q, 0, 0, 0);
        R = __builtin_amdgcn_mfma_f32_16x16x32_bf16(ha0, *(const bf16x8*)(br), R, 0, 0, 0);
        R = __builtin_amdgcn_mfma_f32_16x16x32_bf16(ha1, *(const bf16x8*)(br + 32), R, 0, 0, 0);
        int col = jt * 16 + r16;
#pragma unroll
        for (int r = 0; r < 4; r++) {
            int row = base + quad * 4 + r;
            float v = fmaxf(P[r] + Q[r] * R[r], 0.f);
            if (finalLayer) {
                __builtin_nontemporal_store(v, &outf[(size_t)row * 64 + col]);
            } else {
                float vs = v * isq4[r];
                __half hv = __float2half(vs);
                __builtin_nontemporal_store(*(unsigned short*)&hv,
                                            (unsigned short*)outs + (size_t)row * 64 + col);
                unsigned int pb = __builtin_amdgcn_cvt_pk_fp8_f32(vs, vs, 0, false);
                __builtin_nontemporal_store((unsigned char)pb,
                                            &outs8[(size_t)row * 64 + col]);
            }
        }
    }
}

// ---------------------------------------------------------------------------
extern "C" void kernel_launch(void* const* d_in, const int* in_sizes, int n_in,
                              void* d_out, int out_size, void* d_ws, size_t ws_size,
                              hipStream_t stream) {
    const float* x = (const float*)d_in[0];
    const int* edges = (const int*)d_in[1];
    const float* W1 = (const float*)d_in[2];
    const float* b1 = (const float*)d_in[3];
    const float* W2 = (const float*)d_in[4];
    const float* A2a = (const float*)d_in[5];
    const float* A2b = (const float*)d_in[6];
    const float* W3 = (const float*)d_in[7];
    const float* A3a = (const float*)d_in[8];
    const float* A3b = (const float*)d_in[9];
    const float* W4 = (const float*)d_in[10];
    const float* A4a = (const float*)d_in[11];
    const float* A4b = (const float*)d_in[12];
    float* out = (float*)d_out;

    const int* src = edges;
    const int* dst = edges + N_EDGES;

    char* p = (char*)d_ws;
    auto alloc = [&](size_t bytes) {
        char* r = p;
        p += (bytes + 255) & ~(size_t)255;
        return r;
    };
    int* bucketCnt        = (int*)alloc(NBKT * 4);
    unsigned int* bktArr  = (unsigned int*)alloc((size_t)NBKT * BKT_CAP * 4);
    int* cnt              = (int*)alloc(N_NODES * 4);                 // full degree
    float* isq            = (float*)alloc(N_NODES * 4);
    float* sdeg           = (float*)alloc(N_NODES * 4);
    unsigned short* srcAp = (unsigned short*)alloc((size_t)N_NODES * ROWCAP * 2);
    unsigned short* wpAll = (unsigned short*)alloc(W_TOTAL * 2);
    __half* Ht            = (__half*)alloc((size_t)N_NODES * 64 * 2);
    __half* As            = (__half*)alloc((size_t)N_NODES * 64 * 2);
    __half* Bs            = (__half*)alloc((size_t)N_NODES * 64 * 2);
    unsigned char* As8    = (unsigned char*)alloc((size_t)(N_NODES + 1) * 64);  // +zero row
    unsigned char* Bs8    = (unsigned char*)alloc((size_t)(N_NODES + 1) * 64);

    const unsigned short* W2p  = wpAll + 8192;
    const unsigned short* A2ap = wpAll + 16384;
    const unsigned short* A2bp = wpAll + 20480;
    const unsigned short* W3p  = wpAll + 24576;
    const unsigned short* A3ap = wpAll + 32768;
    const unsigned short* A3bp = wpAll + 36864;
    const unsigned short* W4p  = wpAll + 40960;
    const unsigned short* A4ap = wpAll + 49152;
    const unsigned short* A4bp = wpAll + 53248;

    hipMemsetAsync(bucketCnt, 0, NBKT * 4, stream);
    hipMemsetAsync(As8 + (size_t)ZROW * 64, 0, 64, stream);   // zero pad-row
    hipMemsetAsync(Bs8 + (size_t)ZROW * 64, 0, 64, stream);

    // ---- pass A: bin edges || layer1 || weight pack ----
    passA_kernel<<<ABLK + TB + WB2, 256, 0, stream>>>(
        x, src, dst, W1, b1, W2, A2a, A2b, W3, A3a, A3b, W4, A4a, A4b,
        bucketCnt, bktArr, wpAll, Ht);

    // ---- pass B: per-bucket CSR build + scale (fused) ----
    csr_scale_k<<<NBKT, 256, 0, stream>>>(bucketCnt, bktArr, Ht, srcAp, cnt,
                                          As, As8, isq, sdeg);

    // ---- layer 2: As -> Bs (MEASUREMENT: reps=2, exact-halved) ----
    conv_dense_k<<<TB, 256, 0, stream>>>(As, As8, cnt, srcAp, isq, sdeg,
                                         W2p, A2ap, A2bp, Bs, Bs8, nullptr, 0, 2);
    // ---- layer 3: Bs -> As ----
    conv_dense_k<<<TB, 256, 0, stream>>>(Bs, Bs8, cnt, srcAp, isq, sdeg,
                                         W3p, A3ap, A3bp, As, As8, nullptr, 0, 1);
    // ---- layer 4: As -> out (fp32) ----
    conv_dense_k<<<TB, 256, 0, stream>>>(As, As8, cnt, srcAp, isq, sdeg,
                                         W4p, A4ap, A4bp, nullptr, nullptr, out, 1, 1);
}

// Round 9
// 235.909 us; speedup vs baseline: 1.0161x; 1.0161x over previous
//
#include <hip/hip_runtime.h>
#include <hip/hip_bf16.h>
#include <hip/hip_fp16.h>

#define N_NODES 50000
#define N_EDGES 800000
#define NTILES 3125        // N_NODES / 16
#define W_TOTAL 57344      // packed bf16 weight elements (W1 slot unused)
#define WB2 192            // pack blocks (W2..A4b = 49152 elems)
#define TB 782             // layer1/dense MFMA blocks (4 waves each)
#define ROWCAP 64          // padded-CSR slots per node (deg mean 16, 12-sigma safe)
#define ZROW N_NODES       // index of the all-zero fp8 row used for slot padding

#define NBKT 200           // dst-range buckets
#define BKT_NODES 250      // nodes per bucket (200*250 = 50000)
#define BKT_CAP 4400       // edges per bucket capacity (mean 4000, +6.3 sigma)
#define ABLK 256           // bin blocks (phase A)
#define ACH ((N_EDGES + ABLK - 1) / ABLK)   // 3125 edges per bin block

typedef __attribute__((ext_vector_type(8))) short bf16x8;          // MFMA A/B frag
typedef __attribute__((ext_vector_type(4))) float f32x4;           // MFMA C/D frag
typedef __attribute__((ext_vector_type(2))) float f32x2;           // packed f32 pair
typedef __attribute__((ext_vector_type(8))) unsigned short u16x8;  // 16B load/store
typedef __attribute__((ext_vector_type(4))) unsigned int u32x4;    // 16B load (ext-vec for nt builtins)

__device__ inline unsigned short f2bf(float f) {  // round-to-nearest-even
    unsigned int x = __float_as_uint(f);
    unsigned int r = (x + 0x7FFF + ((x >> 16) & 1)) >> 16;
    return (unsigned short)r;
}
__device__ inline float2 h2f2(unsigned int u) {   // packed half2 -> float2
    __half2 h = *(__half2*)&u;
    return make_float2(__low2float(h), __high2float(h));
}
__device__ inline unsigned int f22h2(float a, float b) {  // 2 floats -> packed half2
    __half2 h = __floats2half2_rn(a, b);
    return *(unsigned int*)&h;
}

// ---------------------------------------------------------------------------
// PASS A (one launch, three independent block roles):
//  [0, ABLK)        : edge BINNING by dst-range (LDS histogram + one global
//                     atomic per (block,bucket), packed (dl<<16|src) run writes).
//  [ABLK, +TB)      : layer1 MFMA -> UNSCALED h (fp16) in Ht.
//  [ABLK+TB, end)   : bf16-pack W2..A4b into wpAll[8192..].
__global__ __launch_bounds__(256) void passA_kernel(
    const float* __restrict__ x, const int* __restrict__ src, const int* __restrict__ dst,
    const float* __restrict__ W1, const float* __restrict__ b1,
    const float* W2, const float* A2a, const float* A2b,
    const float* W3, const float* A3a, const float* A3b,
    const float* W4, const float* A4a, const float* A4b,
    int* __restrict__ bucketCnt, unsigned int* __restrict__ bktArr,
    unsigned short* __restrict__ wp, __half* __restrict__ Ht) {
    int tid = threadIdx.x;

    if (blockIdx.x < ABLK) {                      // ---- bin edges ----
        __shared__ int hist[NBKT];
        __shared__ int gbase[NBKT];
        __shared__ int hoff[NBKT];
        if (tid < NBKT) { hist[tid] = 0; hoff[tid] = 0; }
        __syncthreads();
        int e0 = blockIdx.x * ACH;
        int e1 = min(e0 + ACH, N_EDGES);
        for (int e = e0 + tid; e < e1; e += 256)
            atomicAdd(&hist[dst[e] / BKT_NODES], 1);
        __syncthreads();
        if (tid < NBKT) {
            int h = hist[tid];
            gbase[tid] = h ? atomicAdd(&bucketCnt[tid], h) : 0;
        }
        __syncthreads();
        for (int e = e0 + tid; e < e1; e += 256) {
            int d = dst[e];
            int b = d / BKT_NODES;
            int pos = gbase[b] + atomicAdd(&hoff[b], 1);
            if (pos < BKT_CAP)
                bktArr[(size_t)b * BKT_CAP + pos] =
                    ((unsigned int)(d - b * BKT_NODES) << 16) | (unsigned int)src[e];
        }
        return;
    }
    if (blockIdx.x >= ABLK + TB) {                // ---- pack W2..A4b ----
        int i = 8192 + (blockIdx.x - ABLK - TB) * 256 + tid;
        if (i >= W_TOTAL) return;
        float v;
        if (i < 16384)      v = W2[i - 8192];
        else if (i < 20480) v = A2a[i - 16384];
        else if (i < 24576) v = A2b[i - 20480];
        else if (i < 32768) v = W3[i - 24576];
        else if (i < 36864) v = A3a[i - 32768];
        else if (i < 40960) v = A3b[i - 36864];
        else if (i < 49152) v = W4[i - 40960];
        else if (i < 53248) v = A4a[i - 49152];
        else                v = A4b[i - 53248];
        wp[i] = f2bf(v);
        return;
    }

    // ---- layer1: h = relu(x @ W1^T + b1) -> Ht (fp16, unscaled) ----
    int wave = ((blockIdx.x - ABLK) * 256 + tid) >> 6;
    if (wave >= NTILES) return;
    int lane = tid & 63;
    int r16 = lane & 15, quad = lane >> 4;
    int base = wave * 16;

    bf16x8 a[4];
    const float* xr = x + (size_t)(base + r16) * 128 + quad * 8;
#pragma unroll
    for (int kb = 0; kb < 4; kb++) {
        float4 f0 = *(const float4*)(xr + kb * 32);
        float4 f1 = *(const float4*)(xr + kb * 32 + 4);
        bf16x8 v;
        v[0] = (short)f2bf(f0.x); v[1] = (short)f2bf(f0.y);
        v[2] = (short)f2bf(f0.z); v[3] = (short)f2bf(f0.w);
        v[4] = (short)f2bf(f1.x); v[5] = (short)f2bf(f1.y);
        v[6] = (short)f2bf(f1.z); v[7] = (short)f2bf(f1.w);
        a[kb] = v;
    }

#pragma unroll
    for (int jt = 0; jt < 4; jt++) {
        f32x4 acc = {0.f, 0.f, 0.f, 0.f};
        const float* wr = W1 + (size_t)(jt * 16 + r16) * 128 + quad * 8;
#pragma unroll
        for (int kb = 0; kb < 4; kb++) {
            float4 g0 = *(const float4*)(wr + kb * 32);
            float4 g1 = *(const float4*)(wr + kb * 32 + 4);
            bf16x8 b;
            b[0] = (short)f2bf(g0.x); b[1] = (short)f2bf(g0.y);
            b[2] = (short)f2bf(g0.z); b[3] = (short)f2bf(g0.w);
            b[4] = (short)f2bf(g1.x); b[5] = (short)f2bf(g1.y);
            b[6] = (short)f2bf(g1.z); b[7] = (short)f2bf(g1.w);
            acc = __builtin_amdgcn_mfma_f32_16x16x32_bf16(a[kb], b, acc, 0, 0, 0);
        }
        int col = jt * 16 + r16;
        float bias = b1[col];
#pragma unroll
        for (int r = 0; r < 4; r++) {
            int row = base + quad * 4 + r;
            float v = fmaxf(acc[r] + bias, 0.f);
            Ht[(size_t)row * 64 + col] = __float2half(v);
        }
    }
}

// ---------------------------------------------------------------------------
// PASS B (csr + scale FUSED): one block per bucket.
//  1) slot assignment via LDS atomics; scattered 2B stores confined to the
//     bucket's 32 KB srcAp region (L2-resident).
//  2) ZROW padding + cnt/isq/sdeg from the LDS degrees.
//  3) scale its 250 rows: As = Ht*isq (fp16), As8 = fp8 e4m3 gather copy.
__global__ __launch_bounds__(256) void csr_scale_k(const int* __restrict__ bucketCnt,
                                                   const unsigned int* __restrict__ bktArr,
                                                   const __half* __restrict__ Ht,
                                                   unsigned short* __restrict__ srcAp,
                                                   int* __restrict__ cnt,
                                                   __half* __restrict__ As,
                                                   unsigned char* __restrict__ As8,
                                                   float* __restrict__ isq,
                                                   float* __restrict__ sdeg) {
    __shared__ int lcnt[BKT_NODES];
    int b = blockIdx.x, tid = threadIdx.x;
    if (tid < BKT_NODES) lcnt[tid] = 0;
    __syncthreads();
    int n = min(bucketCnt[b], BKT_CAP);
    int rowbase = b * BKT_NODES;
    const unsigned int* arr = bktArr + (size_t)b * BKT_CAP;
    for (int i = tid; i < n; i += 256) {
        unsigned int u = arr[i];
        int dl = (int)(u >> 16);
        int pos = atomicAdd(&lcnt[dl], 1);
        if (pos < ROWCAP)
            srcAp[(size_t)(rowbase + dl) * ROWCAP + pos] = (unsigned short)(u & 0xFFFF);
    }
    __syncthreads();
    if (tid < BKT_NODES) {
        int deg = lcnt[tid];
        int cv = min(deg, ROWCAP);
        int cvr = (cv + 7) & ~7;
        for (int j = cv; j < cvr; j++)
            srcAp[(size_t)(rowbase + tid) * ROWCAP + j] = (unsigned short)ZROW;
        cnt[rowbase + tid] = deg;
        float dv = fmaxf((float)deg, 1.0f);
        isq[rowbase + tid] = rsqrtf(dv);
        sdeg[rowbase + tid] = sqrtf(dv);
    }
    __syncthreads();
    // scale: 16 threads per row, 16 rows per sweep
    int sl = tid & 15;
    for (int rr = tid >> 4; rr < BKT_NODES; rr += 16) {
        int row = rowbase + rr;
        float is = rsqrtf(fmaxf((float)lcnt[rr], 1.0f));
        uint2 rv = *((const uint2*)(Ht + (size_t)row * 64) + sl);   // 4 halves
        float2 fa = h2f2(rv.x), fb = h2f2(rv.y);
        float s0 = fa.x * is, s1 = fa.y * is, s2 = fb.x * is, s3 = fb.y * is;
        uint2 ov;
        ov.x = f22h2(s0, s1);
        ov.y = f22h2(s2, s3);
        *((uint2*)(As + (size_t)row * 64) + sl) = ov;
        unsigned int w = __builtin_amdgcn_cvt_pk_fp8_f32(s0, s1, 0, false);
        w = __builtin_amdgcn_cvt_pk_fp8_f32(s2, s3, w, true);
        ((unsigned int*)As8)[(size_t)row * 16 + sl] = w;            // 4 fp8 bytes
    }
}

// ---------------------------------------------------------------------------
// FUSED conv + dense, one block = 64 rows (4 MFMA tiles, wave-independent).
// R8: L2 WARM-UP preamble -- R7's reps=2 probe measured the L2-warm gather
//   pass at 12.8us vs a cold first pass ~25us: the gather is cold-miss bound
//   (hs8 is L3-resident after the producing kernel's flush; per-XCD L2s start
//   cold each dispatch). Each block streams a ~33KB slice of hs8 with plain
//   loads, sliced by blockIdx>>3 so (under round-robin block->XCD dispatch)
//   every XCD pulls the whole 3.2MB into ITS L2 sequentially (~25.6MB L3
//   traffic chip-wide, ~4us, overlapped). Heuristic only -- correctness never
//   depends on the mapping.
// conv: 16 rows x 4 feat-lanes, 16B fp8 gathers; one wave instr = 16 edges.
// dense: fp16 path; fp8 error enters ONLY through the conv half of concat.
__global__ __launch_bounds__(256) void conv_dense_k(const __half* __restrict__ hs,
                                                    const unsigned char* __restrict__ hs8,
                                                    const int* __restrict__ cnt,
                                                    const unsigned short* __restrict__ srcAp,
                                                    const float* __restrict__ isq,
                                                    const float* __restrict__ sdeg,
                                                    const unsigned short* __restrict__ wp,
                                                    const unsigned short* __restrict__ aap,
                                                    const unsigned short* __restrict__ abp,
                                                    __half* __restrict__ outs,
                                                    unsigned char* __restrict__ outs8,
                                                    float* __restrict__ outf,
                                                    int finalLayer) {
    __shared__ unsigned short clds[64][64];   // conv result (bf16), 8 KB
    int tid = threadIdx.x;
    int wv = tid >> 6;
    int lane = tid & 63;

    // ---- L2 warm-up: per-XCD sequential prefetch of the fp8 gather array ----
    {
        const int NSLICE = (TB + 7) >> 3;                    // 98 slices per XCD
        int slice = blockIdx.x >> 3;                         // round-robin heuristic
        if (slice < NSLICE) {
            const size_t nvec = ((size_t)(N_NODES + 1) * 64) >> 4;   // 16B units
            size_t per = (nvec + NSLICE - 1) / NSLICE;
            size_t s0 = (size_t)slice * per;
            size_t s1 = s0 + per; if (s1 > nvec) s1 = nvec;
            const u32x4* pf = (const u32x4*)hs8;
            for (size_t i = s0 + tid; i < s1; i += 256) {
                u32x4 v = pf[i];
                asm volatile("" :: "v"(v[0]), "v"(v[1]), "v"(v[2]), "v"(v[3]));
            }
        }
    }

    int t = blockIdx.x * 4 + wv;
    if (t >= NTILES) return;
    int base = t * 16;   // N_NODES % 16 == 0: all rows valid

    // ---- conv phase (no barrier: wave reads only its own clds quarter) ----
    {
        int r = lane >> 2, fl = lane & 3;      // 16 rows x 4 feat-lanes
        int row = base + r;
        int b = row * ROWCAP;
        int cv = min(cnt[row], ROWCAP);
        int cvr = (cv + 7) & ~7;               // slots [cv,cvr) = ZROW (zeros)
        f32x2 acc[8];
#pragma unroll
        for (int k = 0; k < 8; k++) acc[k] = (f32x2){0.f, 0.f};
        if (cvr) {
            u16x8 sv = __builtin_nontemporal_load((const u16x8*)(srcAp + b));
            for (int i = 0; i < cvr; i += 8) {
                u16x8 svn = sv;                // prefetch next slot vector
                if (i + 8 < cvr)
                    svn = __builtin_nontemporal_load((const u16x8*)(srcAp + b + i + 8));
                u32x4 rv[8];
#pragma unroll
                for (int u = 0; u < 8; u++)
                    rv[u] = *((const u32x4*)(hs8 + (size_t)(int)sv[u] * 64) + fl);
#pragma unroll
                for (int u = 0; u < 8; u++) {
                    acc[0] += __builtin_amdgcn_cvt_pk_f32_fp8(rv[u][0], false);
                    acc[1] += __builtin_amdgcn_cvt_pk_f32_fp8(rv[u][0], true);
                    acc[2] += __builtin_amdgcn_cvt_pk_f32_fp8(rv[u][1], false);
                    acc[3] += __builtin_amdgcn_cvt_pk_f32_fp8(rv[u][1], true);
                    acc[4] += __builtin_amdgcn_cvt_pk_f32_fp8(rv[u][2], false);
                    acc[5] += __builtin_amdgcn_cvt_pk_f32_fp8(rv[u][2], true);
                    acc[6] += __builtin_amdgcn_cvt_pk_f32_fp8(rv[u][3], false);
                    acc[7] += __builtin_amdgcn_cvt_pk_f32_fp8(rv[u][3], true);
                }
                sv = svn;
            }
        }
        float sc = isq[row];
        u16x8 o0, o1;
#pragma unroll
        for (int k = 0; k < 4; k++) {
            o0[2 * k]     = f2bf(acc[k][0] * sc);
            o0[2 * k + 1] = f2bf(acc[k][1] * sc);
            o1[2 * k]     = f2bf(acc[4 + k][0] * sc);
            o1[2 * k + 1] = f2bf(acc[4 + k][1] * sc);
        }
        // lane (r,fl) owns feats [fl*16, fl*16+16) of its row
        *(u16x8*)(&clds[wv * 16 + r][fl * 16]) = o0;
        *(u16x8*)(&clds[wv * 16 + r][fl * 16 + 8]) = o1;
    }

    // ---- dense phase ----
    int r16 = lane & 15, quad = lane >> 4;
    float rs = sdeg[base + r16];                 // h = hs * sqrt(deg), per A-row
    const u32x4* hp = (const u32x4*)(hs + (size_t)(base + r16) * 64);
    u32x4 raw0 = __builtin_nontemporal_load(hp + quad);      // feats quad*8 .. +8
    u32x4 raw1 = __builtin_nontemporal_load(hp + 4 + quad);  // feats 32+quad*8 .. +8
    bf16x8 ha0, ha1;
    {
        float2 f;
        f = h2f2(raw0[0]); ha0[0] = (short)f2bf(f.x * rs); ha0[1] = (short)f2bf(f.y * rs);
        f = h2f2(raw0[1]); ha0[2] = (short)f2bf(f.x * rs); ha0[3] = (short)f2bf(f.y * rs);
        f = h2f2(raw0[2]); ha0[4] = (short)f2bf(f.x * rs); ha0[5] = (short)f2bf(f.y * rs);
        f = h2f2(raw0[3]); ha0[6] = (short)f2bf(f.x * rs); ha0[7] = (short)f2bf(f.y * rs);
        f = h2f2(raw1[0]); ha1[0] = (short)f2bf(f.x * rs); ha1[1] = (short)f2bf(f.y * rs);
        f = h2f2(raw1[1]); ha1[2] = (short)f2bf(f.x * rs); ha1[3] = (short)f2bf(f.y * rs);
        f = h2f2(raw1[2]); ha1[4] = (short)f2bf(f.x * rs); ha1[5] = (short)f2bf(f.y * rs);
        f = h2f2(raw1[3]); ha1[6] = (short)f2bf(f.x * rs); ha1[7] = (short)f2bf(f.y * rs);
    }
    bf16x8 ca0 = *(const bf16x8*)(&clds[wv * 16 + r16][quad * 8]);
    bf16x8 ca1 = *(const bf16x8*)(&clds[wv * 16 + r16][32 + quad * 8]);

    float isq4[4];
    if (!finalLayer) {
#pragma unroll
        for (int r = 0; r < 4; r++) isq4[r] = isq[base + quad * 4 + r];
    }

#pragma unroll
    for (int jt = 0; jt < 4; jt++) {
        const unsigned short* wr = wp + (size_t)(jt * 16 + r16) * 128 + quad * 8;
        const unsigned short* ar = aap + (size_t)(jt * 16 + r16) * 64 + quad * 8;
        const unsigned short* br = abp + (size_t)(jt * 16 + r16) * 64 + quad * 8;
        f32x4 P = {0.f, 0.f, 0.f, 0.f};
        f32x4 Q = {0.f, 0.f, 0.f, 0.f};
        f32x4 R = {0.f, 0.f, 0.f, 0.f};
        P = __builtin_amdgcn_mfma_f32_16x16x32_bf16(ha0, *(const bf16x8*)(wr), P, 0, 0, 0);
        P = __builtin_amdgcn_mfma_f32_16x16x32_bf16(ha1, *(const bf16x8*)(wr + 32), P, 0, 0, 0);
        P = __builtin_amdgcn_mfma_f32_16x16x32_bf16(ca0, *(const bf16x8*)(wr + 64), P, 0, 0, 0);
        P = __builtin_amdgcn_mfma_f32_16x16x32_bf16(ca1, *(const bf16x8*)(wr + 96), P, 0, 0, 0);
        Q = __builtin_amdgcn_mfma_f32_16x16x32_bf16(ha0, *(const bf16x8*)(ar), Q, 0, 0, 0);
        Q = __builtin_amdgcn_mfma_f32_16x16x32_bf16(ha1, *(const bf16x8*)(ar + 32), Q, 0, 0, 0);
        R = __builtin_amdgcn_mfma_f32_16x16x32_bf16(ha0, *(const bf16x8*)(br), R, 0, 0, 0);
        R = __builtin_amdgcn_mfma_f32_16x16x32_bf16(ha1, *(const bf16x8*)(br + 32), R, 0, 0, 0);
        int col = jt * 16 + r16;
#pragma unroll
        for (int r = 0; r < 4; r++) {
            int row = base + quad * 4 + r;
            float v = fmaxf(P[r] + Q[r] * R[r], 0.f);
            if (finalLayer) {
                __builtin_nontemporal_store(v, &outf[(size_t)row * 64 + col]);
            } else {
                float vs = v * isq4[r];
                __half hv = __float2half(vs);
                __builtin_nontemporal_store(*(unsigned short*)&hv,
                                            (unsigned short*)outs + (size_t)row * 64 + col);
                unsigned int pb = __builtin_amdgcn_cvt_pk_fp8_f32(vs, vs, 0, false);
                outs8[(size_t)row * 64 + col] = (unsigned char)pb;  // CACHED: next layer's gather source
            }
        }
    }
}

// ---------------------------------------------------------------------------
extern "C" void kernel_launch(void* const* d_in, const int* in_sizes, int n_in,
                              void* d_out, int out_size, void* d_ws, size_t ws_size,
                              hipStream_t stream) {
    const float* x = (const float*)d_in[0];
    const int* edges = (const int*)d_in[1];
    const float* W1 = (const float*)d_in[2];
    const float* b1 = (const float*)d_in[3];
    const float* W2 = (const float*)d_in[4];
    const float* A2a = (const float*)d_in[5];
    const float* A2b = (const float*)d_in[6];
    const float* W3 = (const float*)d_in[7];
    const float* A3a = (const float*)d_in[8];
    const float* A3b = (const float*)d_in[9];
    const float* W4 = (const float*)d_in[10];
    const float* A4a = (const float*)d_in[11];
    const float* A4b = (const float*)d_in[12];
    float* out = (float*)d_out;

    const int* src = edges;
    const int* dst = edges + N_EDGES;

    char* p = (char*)d_ws;
    auto alloc = [&](size_t bytes) {
        char* r = p;
        p += (bytes + 255) & ~(size_t)255;
        return r;
    };
    int* bucketCnt        = (int*)alloc(NBKT * 4);
    unsigned int* bktArr  = (unsigned int*)alloc((size_t)NBKT * BKT_CAP * 4);
    int* cnt              = (int*)alloc(N_NODES * 4);                 // full degree
    float* isq            = (float*)alloc(N_NODES * 4);
    float* sdeg           = (float*)alloc(N_NODES * 4);
    unsigned short* srcAp = (unsigned short*)alloc((size_t)N_NODES * ROWCAP * 2);
    unsigned short* wpAll = (unsigned short*)alloc(W_TOTAL * 2);
    __half* Ht            = (__half*)alloc((size_t)N_NODES * 64 * 2);
    __half* As            = (__half*)alloc((size_t)N_NODES * 64 * 2);
    __half* Bs            = (__half*)alloc((size_t)N_NODES * 64 * 2);
    unsigned char* As8    = (unsigned char*)alloc((size_t)(N_NODES + 1) * 64);  // +zero row
    unsigned char* Bs8    = (unsigned char*)alloc((size_t)(N_NODES + 1) * 64);

    const unsigned short* W2p  = wpAll + 8192;
    const unsigned short* A2ap = wpAll + 16384;
    const unsigned short* A2bp = wpAll + 20480;
    const unsigned short* W3p  = wpAll + 24576;
    const unsigned short* A3ap = wpAll + 32768;
    const unsigned short* A3bp = wpAll + 36864;
    const unsigned short* W4p  = wpAll + 40960;
    const unsigned short* A4ap = wpAll + 49152;
    const unsigned short* A4bp = wpAll + 53248;

    hipMemsetAsync(bucketCnt, 0, NBKT * 4, stream);
    hipMemsetAsync(As8 + (size_t)ZROW * 64, 0, 64, stream);   // zero pad-row
    hipMemsetAsync(Bs8 + (size_t)ZROW * 64, 0, 64, stream);

    // ---- pass A: bin edges || layer1 || weight pack ----
    passA_kernel<<<ABLK + TB + WB2, 256, 0, stream>>>(
        x, src, dst, W1, b1, W2, A2a, A2b, W3, A3a, A3b, W4, A4a, A4b,
        bucketCnt, bktArr, wpAll, Ht);

    // ---- pass B: per-bucket CSR build + scale (fused) ----
    csr_scale_k<<<NBKT, 256, 0, stream>>>(bucketCnt, bktArr, Ht, srcAp, cnt,
                                          As, As8, isq, sdeg);

    // ---- layer 2: As -> Bs ----
    conv_dense_k<<<TB, 256, 0, stream>>>(As, As8, cnt, srcAp, isq, sdeg,
                                         W2p, A2ap, A2bp, Bs, Bs8, nullptr, 0);
    // ---- layer 3: Bs -> As ----
    conv_dense_k<<<TB, 256, 0, stream>>>(Bs, Bs8, cnt, srcAp, isq, sdeg,
                                         W3p, A3ap, A3bp, As, As8, nullptr, 0);
    // ---- layer 4: As -> out (fp32) ----
    conv_dense_k<<<TB, 256, 0, stream>>>(As, As8, cnt, srcAp, isq, sdeg,
                                         W4p, A4ap, A4bp, nullptr, nullptr, out, 1);
}

// Round 10
// 232.184 us; speedup vs baseline: 1.0324x; 1.0160x over previous
//
#include <hip/hip_runtime.h>
#include <hip/hip_bf16.h>
#include <hip/hip_fp16.h>

#define N_NODES 50000
#define N_EDGES 800000
#define NTILES 3125        // N_NODES / 16
#define W_TOTAL 57344      // packed bf16 weight elements (W1 slot unused)
#define WB2 192            // pack blocks (W2..A4b = 49152 elems)
#define TB 782             // layer1/dense MFMA blocks (4 waves each)
#define ROWCAP 64          // padded-CSR slots per node (deg mean 16, 12-sigma safe)
#define ZROW N_NODES       // index of the all-zero fp8 row used for slot padding

#define NBKT 200           // dst-range buckets
#define BKT_NODES 250      // nodes per bucket (200*250 = 50000)
#define BKT_CAP 4400       // edges per bucket capacity (mean 4000, +6.3 sigma)
#define ABLK 256           // bin blocks (phase A)
#define ACH ((N_EDGES + ABLK - 1) / ABLK)   // 3125 edges per bin block

typedef __attribute__((ext_vector_type(8))) short bf16x8;          // MFMA A/B frag
typedef __attribute__((ext_vector_type(4))) float f32x4;           // MFMA C/D frag
typedef __attribute__((ext_vector_type(2))) float f32x2;           // packed f32 pair
typedef __attribute__((ext_vector_type(8))) unsigned short u16x8;  // 16B load/store
typedef __attribute__((ext_vector_type(4))) unsigned int u32x4;    // 16B load (ext-vec for nt builtins)

__device__ inline unsigned short f2bf(float f) {  // round-to-nearest-even
    unsigned int x = __float_as_uint(f);
    unsigned int r = (x + 0x7FFF + ((x >> 16) & 1)) >> 16;
    return (unsigned short)r;
}
__device__ inline float2 h2f2(unsigned int u) {   // packed half2 -> float2
    __half2 h = *(__half2*)&u;
    return make_float2(__low2float(h), __high2float(h));
}
__device__ inline unsigned int f22h2(float a, float b) {  // 2 floats -> packed half2
    __half2 h = __floats2half2_rn(a, b);
    return *(unsigned int*)&h;
}

// ---------------------------------------------------------------------------
// PASS A (one launch, three independent block roles):
//  [0, ABLK)        : edge BINNING by dst-range (LDS histogram + one global
//                     atomic per (block,bucket), packed (dl<<16|src) run writes).
//  [ABLK, +TB)      : layer1 MFMA -> UNSCALED h (fp16) in Ht.
//  [ABLK+TB, end)   : bf16-pack W2..A4b into wpAll[8192..].
__global__ __launch_bounds__(256) void passA_kernel(
    const float* __restrict__ x, const int* __restrict__ src, const int* __restrict__ dst,
    const float* __restrict__ W1, const float* __restrict__ b1,
    const float* W2, const float* A2a, const float* A2b,
    const float* W3, const float* A3a, const float* A3b,
    const float* W4, const float* A4a, const float* A4b,
    int* __restrict__ bucketCnt, unsigned int* __restrict__ bktArr,
    unsigned short* __restrict__ wp, __half* __restrict__ Ht) {
    int tid = threadIdx.x;

    if (blockIdx.x < ABLK) {                      // ---- bin edges ----
        __shared__ int hist[NBKT];
        __shared__ int gbase[NBKT];
        __shared__ int hoff[NBKT];
        if (tid < NBKT) { hist[tid] = 0; hoff[tid] = 0; }
        __syncthreads();
        int e0 = blockIdx.x * ACH;
        int e1 = min(e0 + ACH, N_EDGES);
        for (int e = e0 + tid; e < e1; e += 256)
            atomicAdd(&hist[dst[e] / BKT_NODES], 1);
        __syncthreads();
        if (tid < NBKT) {
            int h = hist[tid];
            gbase[tid] = h ? atomicAdd(&bucketCnt[tid], h) : 0;
        }
        __syncthreads();
        for (int e = e0 + tid; e < e1; e += 256) {
            int d = dst[e];
            int b = d / BKT_NODES;
            int pos = gbase[b] + atomicAdd(&hoff[b], 1);
            if (pos < BKT_CAP)
                bktArr[(size_t)b * BKT_CAP + pos] =
                    ((unsigned int)(d - b * BKT_NODES) << 16) | (unsigned int)src[e];
        }
        return;
    }
    if (blockIdx.x >= ABLK + TB) {                // ---- pack W2..A4b ----
        int i = 8192 + (blockIdx.x - ABLK - TB) * 256 + tid;
        if (i >= W_TOTAL) return;
        float v;
        if (i < 16384)      v = W2[i - 8192];
        else if (i < 20480) v = A2a[i - 16384];
        else if (i < 24576) v = A2b[i - 20480];
        else if (i < 32768) v = W3[i - 24576];
        else if (i < 36864) v = A3a[i - 32768];
        else if (i < 40960) v = A3b[i - 36864];
        else if (i < 49152) v = W4[i - 40960];
        else if (i < 53248) v = A4a[i - 49152];
        else                v = A4b[i - 53248];
        wp[i] = f2bf(v);
        return;
    }

    // ---- layer1: h = relu(x @ W1^T + b1) -> Ht (fp16, unscaled) ----
    int wave = ((blockIdx.x - ABLK) * 256 + tid) >> 6;
    if (wave >= NTILES) return;
    int lane = tid & 63;
    int r16 = lane & 15, quad = lane >> 4;
    int base = wave * 16;

    bf16x8 a[4];
    const float* xr = x + (size_t)(base + r16) * 128 + quad * 8;
#pragma unroll
    for (int kb = 0; kb < 4; kb++) {
        float4 f0 = *(const float4*)(xr + kb * 32);
        float4 f1 = *(const float4*)(xr + kb * 32 + 4);
        bf16x8 v;
        v[0] = (short)f2bf(f0.x); v[1] = (short)f2bf(f0.y);
        v[2] = (short)f2bf(f0.z); v[3] = (short)f2bf(f0.w);
        v[4] = (short)f2bf(f1.x); v[5] = (short)f2bf(f1.y);
        v[6] = (short)f2bf(f1.z); v[7] = (short)f2bf(f1.w);
        a[kb] = v;
    }

#pragma unroll
    for (int jt = 0; jt < 4; jt++) {
        f32x4 acc = {0.f, 0.f, 0.f, 0.f};
        const float* wr = W1 + (size_t)(jt * 16 + r16) * 128 + quad * 8;
#pragma unroll
        for (int kb = 0; kb < 4; kb++) {
            float4 g0 = *(const float4*)(wr + kb * 32);
            float4 g1 = *(const float4*)(wr + kb * 32 + 4);
            bf16x8 b;
            b[0] = (short)f2bf(g0.x); b[1] = (short)f2bf(g0.y);
            b[2] = (short)f2bf(g0.z); b[3] = (short)f2bf(g0.w);
            b[4] = (short)f2bf(g1.x); b[5] = (short)f2bf(g1.y);
            b[6] = (short)f2bf(g1.z); b[7] = (short)f2bf(g1.w);
            acc = __builtin_amdgcn_mfma_f32_16x16x32_bf16(a[kb], b, acc, 0, 0, 0);
        }
        int col = jt * 16 + r16;
        float bias = b1[col];
#pragma unroll
        for (int r = 0; r < 4; r++) {
            int row = base + quad * 4 + r;
            float v = fmaxf(acc[r] + bias, 0.f);
            Ht[(size_t)row * 64 + col] = __float2half(v);
        }
    }
}

// ---------------------------------------------------------------------------
// PASS B (csr + scale FUSED): one block per bucket.
//  1) slot assignment via LDS atomics; scattered 2B stores confined to the
//     bucket's 32 KB srcAp region (L2-resident).
//  2) ZROW padding + cnt/isq/sdeg from the LDS degrees.
//  3) scale its 250 rows: As = Ht*isq (fp16), As8 = fp8 e4m3 gather copy.
__global__ __launch_bounds__(256) void csr_scale_k(const int* __restrict__ bucketCnt,
                                                   const unsigned int* __restrict__ bktArr,
                                                   const __half* __restrict__ Ht,
                                                   unsigned short* __restrict__ srcAp,
                                                   int* __restrict__ cnt,
                                                   __half* __restrict__ As,
                                                   unsigned char* __restrict__ As8,
                                                   float* __restrict__ isq,
                                                   float* __restrict__ sdeg) {
    __shared__ int lcnt[BKT_NODES];
    int b = blockIdx.x, tid = threadIdx.x;
    if (tid < BKT_NODES) lcnt[tid] = 0;
    __syncthreads();
    int n = min(bucketCnt[b], BKT_CAP);
    int rowbase = b * BKT_NODES;
    const unsigned int* arr = bktArr + (size_t)b * BKT_CAP;
    for (int i = tid; i < n; i += 256) {
        unsigned int u = arr[i];
        int dl = (int)(u >> 16);
        int pos = atomicAdd(&lcnt[dl], 1);
        if (pos < ROWCAP)
            srcAp[(size_t)(rowbase + dl) * ROWCAP + pos] = (unsigned short)(u & 0xFFFF);
    }
    __syncthreads();
    if (tid < BKT_NODES) {
        int deg = lcnt[tid];
        int cv = min(deg, ROWCAP);
        int cvr = (cv + 7) & ~7;
        for (int j = cv; j < cvr; j++)
            srcAp[(size_t)(rowbase + tid) * ROWCAP + j] = (unsigned short)ZROW;
        cnt[rowbase + tid] = deg;
        float dv = fmaxf((float)deg, 1.0f);
        isq[rowbase + tid] = rsqrtf(dv);
        sdeg[rowbase + tid] = sqrtf(dv);
    }
    __syncthreads();
    // scale: 16 threads per row, 16 rows per sweep
    int sl = tid & 15;
    for (int rr = tid >> 4; rr < BKT_NODES; rr += 16) {
        int row = rowbase + rr;
        float is = rsqrtf(fmaxf((float)lcnt[rr], 1.0f));
        uint2 rv = *((const uint2*)(Ht + (size_t)row * 64) + sl);   // 4 halves
        float2 fa = h2f2(rv.x), fb = h2f2(rv.y);
        float s0 = fa.x * is, s1 = fa.y * is, s2 = fb.x * is, s3 = fb.y * is;
        uint2 ov;
        ov.x = f22h2(s0, s1);
        ov.y = f22h2(s2, s3);
        *((uint2*)(As + (size_t)row * 64) + sl) = ov;
        unsigned int w = __builtin_amdgcn_cvt_pk_fp8_f32(s0, s1, 0, false);
        w = __builtin_amdgcn_cvt_pk_fp8_f32(s2, s3, w, true);
        ((unsigned int*)As8)[(size_t)row * 16 + sl] = w;            // 4 fp8 bytes
    }
}

// ---------------------------------------------------------------------------
// FUSED conv + dense, one block = 64 rows (4 MFMA tiles, wave-independent).
// conv (R9 -- 2-chunk deep gather): R7's reps=2 probe showed the warm gather
//   pass costs 12.8us vs a ~25us cold first pass: the cold phase is LATENCY
//   bound (compulsory L3->L2 traffic is only ~26MB). Fix: issue TWO slot-
//   vectors' worth of gathers (16 loads/lane) before the first conversion;
//   the compiler's counted vmcnt leaves 8 loads in flight during each
//   conversion -- peak outstanding doubles. deg~Poisson(16) so most rows do
//   exactly one unrolled iteration (cvr==16); 8-slot tail loop for the rest.
//   (R8's per-XCD warm-up prefetch REVERTED: +9us measured -- blocks consume
//   the whole array immediately, before sibling slices land; no barrier, no
//   ordering, pure overhead.)
// dense: fp16 path; fp8 error enters ONLY through the conv half of concat.
__global__ __launch_bounds__(256) void conv_dense_k(const __half* __restrict__ hs,
                                                    const unsigned char* __restrict__ hs8,
                                                    const int* __restrict__ cnt,
                                                    const unsigned short* __restrict__ srcAp,
                                                    const float* __restrict__ isq,
                                                    const float* __restrict__ sdeg,
                                                    const unsigned short* __restrict__ wp,
                                                    const unsigned short* __restrict__ aap,
                                                    const unsigned short* __restrict__ abp,
                                                    __half* __restrict__ outs,
                                                    unsigned char* __restrict__ outs8,
                                                    float* __restrict__ outf,
                                                    int finalLayer) {
    __shared__ unsigned short clds[64][64];   // conv result (bf16), 8 KB
    int tid = threadIdx.x;
    int wv = tid >> 6;
    int lane = tid & 63;
    int t = blockIdx.x * 4 + wv;
    if (t >= NTILES) return;
    int base = t * 16;   // N_NODES % 16 == 0: all rows valid

    // ---- conv phase (no barrier: wave reads only its own clds quarter) ----
    {
        int r = lane >> 2, fl = lane & 3;      // 16 rows x 4 feat-lanes
        int row = base + r;
        int b = row * ROWCAP;
        int cv = min(cnt[row], ROWCAP);
        int cvr = (cv + 7) & ~7;               // slots [cv,cvr) = ZROW (zeros)
        f32x2 acc[8];
#pragma unroll
        for (int k = 0; k < 8; k++) acc[k] = (f32x2){0.f, 0.f};

        int i = 0;
        // 2-chunk unrolled main: 16 gathers in flight before first conversion
        if (cvr >= 16) {
            u16x8 sv0 = __builtin_nontemporal_load((const u16x8*)(srcAp + b));
            u16x8 sv1 = __builtin_nontemporal_load((const u16x8*)(srcAp + b + 8));
            for (; i + 16 <= cvr; i += 16) {
                u16x8 n0 = sv0, n1 = sv1;      // prefetch next pair of slot vectors
                if (i + 24 <= cvr)
                    n0 = __builtin_nontemporal_load((const u16x8*)(srcAp + b + i + 16));
                if (i + 32 <= cvr)
                    n1 = __builtin_nontemporal_load((const u16x8*)(srcAp + b + i + 24));
                u32x4 rv0[8], rv1[8];
#pragma unroll
                for (int u = 0; u < 8; u++)
                    rv0[u] = *((const u32x4*)(hs8 + (size_t)(int)sv0[u] * 64) + fl);
#pragma unroll
                for (int u = 0; u < 8; u++)
                    rv1[u] = *((const u32x4*)(hs8 + (size_t)(int)sv1[u] * 64) + fl);
#pragma unroll
                for (int u = 0; u < 8; u++) {
                    acc[0] += __builtin_amdgcn_cvt_pk_f32_fp8(rv0[u][0], false);
                    acc[1] += __builtin_amdgcn_cvt_pk_f32_fp8(rv0[u][0], true);
                    acc[2] += __builtin_amdgcn_cvt_pk_f32_fp8(rv0[u][1], false);
                    acc[3] += __builtin_amdgcn_cvt_pk_f32_fp8(rv0[u][1], true);
                    acc[4] += __builtin_amdgcn_cvt_pk_f32_fp8(rv0[u][2], false);
                    acc[5] += __builtin_amdgcn_cvt_pk_f32_fp8(rv0[u][2], true);
                    acc[6] += __builtin_amdgcn_cvt_pk_f32_fp8(rv0[u][3], false);
                    acc[7] += __builtin_amdgcn_cvt_pk_f32_fp8(rv0[u][3], true);
                }
#pragma unroll
                for (int u = 0; u < 8; u++) {
                    acc[0] += __builtin_amdgcn_cvt_pk_f32_fp8(rv1[u][0], false);
                    acc[1] += __builtin_amdgcn_cvt_pk_f32_fp8(rv1[u][0], true);
                    acc[2] += __builtin_amdgcn_cvt_pk_f32_fp8(rv1[u][1], false);
                    acc[3] += __builtin_amdgcn_cvt_pk_f32_fp8(rv1[u][1], true);
                    acc[4] += __builtin_amdgcn_cvt_pk_f32_fp8(rv1[u][2], false);
                    acc[5] += __builtin_amdgcn_cvt_pk_f32_fp8(rv1[u][2], true);
                    acc[6] += __builtin_amdgcn_cvt_pk_f32_fp8(rv1[u][3], false);
                    acc[7] += __builtin_amdgcn_cvt_pk_f32_fp8(rv1[u][3], true);
                }
                sv0 = n0; sv1 = n1;
            }
        }
        // tail: at most one 8-slot chunk
        for (; i < cvr; i += 8) {
            u16x8 sv = __builtin_nontemporal_load((const u16x8*)(srcAp + b + i));
            u32x4 rv[8];
#pragma unroll
            for (int u = 0; u < 8; u++)
                rv[u] = *((const u32x4*)(hs8 + (size_t)(int)sv[u] * 64) + fl);
#pragma unroll
            for (int u = 0; u < 8; u++) {
                acc[0] += __builtin_amdgcn_cvt_pk_f32_fp8(rv[u][0], false);
                acc[1] += __builtin_amdgcn_cvt_pk_f32_fp8(rv[u][0], true);
                acc[2] += __builtin_amdgcn_cvt_pk_f32_fp8(rv[u][1], false);
                acc[3] += __builtin_amdgcn_cvt_pk_f32_fp8(rv[u][1], true);
                acc[4] += __builtin_amdgcn_cvt_pk_f32_fp8(rv[u][2], false);
                acc[5] += __builtin_amdgcn_cvt_pk_f32_fp8(rv[u][2], true);
                acc[6] += __builtin_amdgcn_cvt_pk_f32_fp8(rv[u][3], false);
                acc[7] += __builtin_amdgcn_cvt_pk_f32_fp8(rv[u][3], true);
            }
        }

        float sc = isq[row];
        u16x8 o0, o1;
#pragma unroll
        for (int k = 0; k < 4; k++) {
            o0[2 * k]     = f2bf(acc[k][0] * sc);
            o0[2 * k + 1] = f2bf(acc[k][1] * sc);
            o1[2 * k]     = f2bf(acc[4 + k][0] * sc);
            o1[2 * k + 1] = f2bf(acc[4 + k][1] * sc);
        }
        // lane (r,fl) owns feats [fl*16, fl*16+16) of its row
        *(u16x8*)(&clds[wv * 16 + r][fl * 16]) = o0;
        *(u16x8*)(&clds[wv * 16 + r][fl * 16 + 8]) = o1;
    }

    // ---- dense phase ----
    int r16 = lane & 15, quad = lane >> 4;
    float rs = sdeg[base + r16];                 // h = hs * sqrt(deg), per A-row
    const u32x4* hp = (const u32x4*)(hs + (size_t)(base + r16) * 64);
    u32x4 raw0 = __builtin_nontemporal_load(hp + quad);      // feats quad*8 .. +8
    u32x4 raw1 = __builtin_nontemporal_load(hp + 4 + quad);  // feats 32+quad*8 .. +8
    bf16x8 ha0, ha1;
    {
        float2 f;
        f = h2f2(raw0[0]); ha0[0] = (short)f2bf(f.x * rs); ha0[1] = (short)f2bf(f.y * rs);
        f = h2f2(raw0[1]); ha0[2] = (short)f2bf(f.x * rs); ha0[3] = (short)f2bf(f.y * rs);
        f = h2f2(raw0[2]); ha0[4] = (short)f2bf(f.x * rs); ha0[5] = (short)f2bf(f.y * rs);
        f = h2f2(raw0[3]); ha0[6] = (short)f2bf(f.x * rs); ha0[7] = (short)f2bf(f.y * rs);
        f = h2f2(raw1[0]); ha1[0] = (short)f2bf(f.x * rs); ha1[1] = (short)f2bf(f.y * rs);
        f = h2f2(raw1[1]); ha1[2] = (short)f2bf(f.x * rs); ha1[3] = (short)f2bf(f.y * rs);
        f = h2f2(raw1[2]); ha1[4] = (short)f2bf(f.x * rs); ha1[5] = (short)f2bf(f.y * rs);
        f = h2f2(raw1[3]); ha1[6] = (short)f2bf(f.x * rs); ha1[7] = (short)f2bf(f.y * rs);
    }
    bf16x8 ca0 = *(const bf16x8*)(&clds[wv * 16 + r16][quad * 8]);
    bf16x8 ca1 = *(const bf16x8*)(&clds[wv * 16 + r16][32 + quad * 8]);

    float isq4[4];
    if (!finalLayer) {
#pragma unroll
        for (int r = 0; r < 4; r++) isq4[r] = isq[base + quad * 4 + r];
    }

#pragma unroll
    for (int jt = 0; jt < 4; jt++) {
        const unsigned short* wr = wp + (size_t)(jt * 16 + r16) * 128 + quad * 8;
        const unsigned short* ar = aap + (size_t)(jt * 16 + r16) * 64 + quad * 8;
        const unsigned short* br = abp + (size_t)(jt * 16 + r16) * 64 + quad * 8;
        f32x4 P = {0.f, 0.f, 0.f, 0.f};
        f32x4 Q = {0.f, 0.f, 0.f, 0.f};
        f32x4 R = {0.f, 0.f, 0.f, 0.f};
        P = __builtin_amdgcn_mfma_f32_16x16x32_bf16(ha0, *(const bf16x8*)(wr), P, 0, 0, 0);
        P = __builtin_amdgcn_mfma_f32_16x16x32_bf16(ha1, *(const bf16x8*)(wr + 32), P, 0, 0, 0);
        P = __builtin_amdgcn_mfma_f32_16x16x32_bf16(ca0, *(const bf16x8*)(wr + 64), P, 0, 0, 0);
        P = __builtin_amdgcn_mfma_f32_16x16x32_bf16(ca1, *(const bf16x8*)(wr + 96), P, 0, 0, 0);
        Q = __builtin_amdgcn_mfma_f32_16x16x32_bf16(ha0, *(const bf16x8*)(ar), Q, 0, 0, 0);
        Q = __builtin_amdgcn_mfma_f32_16x16x32_bf16(ha1, *(const bf16x8*)(ar + 32), Q, 0, 0, 0);
        R = __builtin_amdgcn_mfma_f32_16x16x32_bf16(ha0, *(const bf16x8*)(br), R, 0, 0, 0);
        R = __builtin_amdgcn_mfma_f32_16x16x32_bf16(ha1, *(const bf16x8*)(br + 32), R, 0, 0, 0);
        int col = jt * 16 + r16;
#pragma unroll
        for (int r = 0; r < 4; r++) {
            int row = base + quad * 4 + r;
            float v = fmaxf(P[r] + Q[r] * R[r], 0.f);
            if (finalLayer) {
                __builtin_nontemporal_store(v, &outf[(size_t)row * 64 + col]);
            } else {
                float vs = v * isq4[r];
                __half hv = __float2half(vs);
                __builtin_nontemporal_store(*(unsigned short*)&hv,
                                            (unsigned short*)outs + (size_t)row * 64 + col);
                unsigned int pb = __builtin_amdgcn_cvt_pk_fp8_f32(vs, vs, 0, false);
                __builtin_nontemporal_store((unsigned char)pb,
                                            &outs8[(size_t)row * 64 + col]);
            }
        }
    }
}

// ---------------------------------------------------------------------------
extern "C" void kernel_launch(void* const* d_in, const int* in_sizes, int n_in,
                              void* d_out, int out_size, void* d_ws, size_t ws_size,
                              hipStream_t stream) {
    const float* x = (const float*)d_in[0];
    const int* edges = (const int*)d_in[1];
    const float* W1 = (const float*)d_in[2];
    const float* b1 = (const float*)d_in[3];
    const float* W2 = (const float*)d_in[4];
    const float* A2a = (const float*)d_in[5];
    const float* A2b = (const float*)d_in[6];
    const float* W3 = (const float*)d_in[7];
    const float* A3a = (const float*)d_in[8];
    const float* A3b = (const float*)d_in[9];
    const float* W4 = (const float*)d_in[10];
    const float* A4a = (const float*)d_in[11];
    const float* A4b = (const float*)d_in[12];
    float* out = (float*)d_out;

    const int* src = edges;
    const int* dst = edges + N_EDGES;

    char* p = (char*)d_ws;
    auto alloc = [&](size_t bytes) {
        char* r = p;
        p += (bytes + 255) & ~(size_t)255;
        return r;
    };
    int* bucketCnt        = (int*)alloc(NBKT * 4);
    unsigned int* bktArr  = (unsigned int*)alloc((size_t)NBKT * BKT_CAP * 4);
    int* cnt              = (int*)alloc(N_NODES * 4);                 // full degree
    float* isq            = (float*)alloc(N_NODES * 4);
    float* sdeg           = (float*)alloc(N_NODES * 4);
    unsigned short* srcAp = (unsigned short*)alloc((size_t)N_NODES * ROWCAP * 2);
    unsigned short* wpAll = (unsigned short*)alloc(W_TOTAL * 2);
    __half* Ht            = (__half*)alloc((size_t)N_NODES * 64 * 2);
    __half* As            = (__half*)alloc((size_t)N_NODES * 64 * 2);
    __half* Bs            = (__half*)alloc((size_t)N_NODES * 64 * 2);
    unsigned char* As8    = (unsigned char*)alloc((size_t)(N_NODES + 1) * 64);  // +zero row
    unsigned char* Bs8    = (unsigned char*)alloc((size_t)(N_NODES + 1) * 64);

    const unsigned short* W2p  = wpAll + 8192;
    const unsigned short* A2ap = wpAll + 16384;
    const unsigned short* A2bp = wpAll + 20480;
    const unsigned short* W3p  = wpAll + 24576;
    const unsigned short* A3ap = wpAll + 32768;
    const unsigned short* A3bp = wpAll + 36864;
    const unsigned short* W4p  = wpAll + 40960;
    const unsigned short* A4ap = wpAll + 49152;
    const unsigned short* A4bp = wpAll + 53248;

    hipMemsetAsync(bucketCnt, 0, NBKT * 4, stream);
    hipMemsetAsync(As8 + (size_t)ZROW * 64, 0, 64, stream);   // zero pad-row
    hipMemsetAsync(Bs8 + (size_t)ZROW * 64, 0, 64, stream);

    // ---- pass A: bin edges || layer1 || weight pack ----
    passA_kernel<<<ABLK + TB + WB2, 256, 0, stream>>>(
        x, src, dst, W1, b1, W2, A2a, A2b, W3, A3a, A3b, W4, A4a, A4b,
        bucketCnt, bktArr, wpAll, Ht);

    // ---- pass B: per-bucket CSR build + scale (fused) ----
    csr_scale_k<<<NBKT, 256, 0, stream>>>(bucketCnt, bktArr, Ht, srcAp, cnt,
                                          As, As8, isq, sdeg);

    // ---- layer 2: As -> Bs ----
    conv_dense_k<<<TB, 256, 0, stream>>>(As, As8, cnt, srcAp, isq, sdeg,
                                         W2p, A2ap, A2bp, Bs, Bs8, nullptr, 0);
    // ---- layer 3: Bs -> As ----
    conv_dense_k<<<TB, 256, 0, stream>>>(Bs, Bs8, cnt, srcAp, isq, sdeg,
                                         W3p, A3ap, A3bp, As, As8, nullptr, 0);
    // ---- layer 4: As -> out (fp32) ----
    conv_dense_k<<<TB, 256, 0, stream>>>(As, As8, cnt, srcAp, isq, sdeg,
                                         W4p, A4ap, A4bp, nullptr, nullptr, out, 1);
}

// Round 11
// 226.547 us; speedup vs baseline: 1.0581x; 1.0249x over previous
//
#include <hip/hip_runtime.h>
#include <hip/hip_bf16.h>
#include <hip/hip_fp16.h>

#define N_NODES 50000
#define N_EDGES 800000
#define NTILES 3125        // N_NODES / 16
#define W_TOTAL 57344      // packed bf16 weight elements (W1 slot unused)
#define WB2 192            // pack blocks (W2..A4b = 49152 elems)
#define TB 782             // layer1/dense MFMA blocks (4 waves each)
#define ROWCAP 64          // padded-CSR slots per node (deg mean 16, 12-sigma safe)
#define ZROW N_NODES       // index of the all-zero fp8 row used for slot padding

#define NBKT 200           // dst-range buckets
#define BKT_NODES 250      // nodes per bucket (200*250 = 50000)
#define BKT_CAP 4400       // edges per bucket capacity (mean 4000, +6.3 sigma)
#define ABLK 256           // bin blocks (phase A)
#define ACH ((N_EDGES + ABLK - 1) / ABLK)   // 3125 edges per bin block

typedef __attribute__((ext_vector_type(8))) short bf16x8;          // MFMA A/B frag
typedef __attribute__((ext_vector_type(4))) float f32x4;           // MFMA C/D frag
typedef __attribute__((ext_vector_type(2))) float f32x2;           // packed f32 pair
typedef __attribute__((ext_vector_type(8))) unsigned short u16x8;  // 16B load/store
typedef __attribute__((ext_vector_type(4))) unsigned int u32x4;    // 16B load (ext-vec for nt builtins)

__device__ inline unsigned short f2bf(float f) {  // round-to-nearest-even
    unsigned int x = __float_as_uint(f);
    unsigned int r = (x + 0x7FFF + ((x >> 16) & 1)) >> 16;
    return (unsigned short)r;
}
__device__ inline float2 h2f2(unsigned int u) {   // packed half2 -> float2
    __half2 h = *(__half2*)&u;
    return make_float2(__low2float(h), __high2float(h));
}
__device__ inline unsigned int f22h2(float a, float b) {  // 2 floats -> packed half2
    __half2 h = __floats2half2_rn(a, b);
    return *(unsigned int*)&h;
}

// ---------------------------------------------------------------------------
// PASS A (one launch, three independent block roles):
//  [0, ABLK)        : edge BINNING by dst-range (LDS histogram + one global
//                     atomic per (block,bucket), packed (dl<<16|src) run writes).
//  [ABLK, +TB)      : layer1 MFMA -> UNSCALED h (fp16) in Ht.
//  [ABLK+TB, end)   : bf16-pack W2..A4b into wpAll[8192..]; first pack block
//                     also zeroes the As8/Bs8 ZROW pad rows (replaces two
//                     64B memset launches -- consumed only after csr_scale).
__global__ __launch_bounds__(256) void passA_kernel(
    const float* __restrict__ x, const int* __restrict__ src, const int* __restrict__ dst,
    const float* __restrict__ W1, const float* __restrict__ b1,
    const float* W2, const float* A2a, const float* A2b,
    const float* W3, const float* A3a, const float* A3b,
    const float* W4, const float* A4a, const float* A4b,
    int* __restrict__ bucketCnt, unsigned int* __restrict__ bktArr,
    unsigned short* __restrict__ wp, __half* __restrict__ Ht,
    unsigned char* __restrict__ As8, unsigned char* __restrict__ Bs8) {
    int tid = threadIdx.x;

    if (blockIdx.x < ABLK) {                      // ---- bin edges ----
        __shared__ int hist[NBKT];
        __shared__ int gbase[NBKT];
        __shared__ int hoff[NBKT];
        if (tid < NBKT) { hist[tid] = 0; hoff[tid] = 0; }
        __syncthreads();
        int e0 = blockIdx.x * ACH;
        int e1 = min(e0 + ACH, N_EDGES);
        for (int e = e0 + tid; e < e1; e += 256)
            atomicAdd(&hist[dst[e] / BKT_NODES], 1);
        __syncthreads();
        if (tid < NBKT) {
            int h = hist[tid];
            gbase[tid] = h ? atomicAdd(&bucketCnt[tid], h) : 0;
        }
        __syncthreads();
        for (int e = e0 + tid; e < e1; e += 256) {
            int d = dst[e];
            int b = d / BKT_NODES;
            int pos = gbase[b] + atomicAdd(&hoff[b], 1);
            if (pos < BKT_CAP)
                bktArr[(size_t)b * BKT_CAP + pos] =
                    ((unsigned int)(d - b * BKT_NODES) << 16) | (unsigned int)src[e];
        }
        return;
    }
    if (blockIdx.x >= ABLK + TB) {                // ---- pack W2..A4b ----
        if (blockIdx.x == ABLK + TB) {            // zero the ZROW pad rows
            if (tid < 16)      ((unsigned int*)(As8 + (size_t)ZROW * 64))[tid] = 0u;
            else if (tid < 32) ((unsigned int*)(Bs8 + (size_t)ZROW * 64))[tid - 16] = 0u;
        }
        int i = 8192 + (blockIdx.x - ABLK - TB) * 256 + tid;
        if (i >= W_TOTAL) return;
        float v;
        if (i < 16384)      v = W2[i - 8192];
        else if (i < 20480) v = A2a[i - 16384];
        else if (i < 24576) v = A2b[i - 20480];
        else if (i < 32768) v = W3[i - 24576];
        else if (i < 36864) v = A3a[i - 32768];
        else if (i < 40960) v = A3b[i - 36864];
        else if (i < 49152) v = W4[i - 40960];
        else if (i < 53248) v = A4a[i - 49152];
        else                v = A4b[i - 53248];
        wp[i] = f2bf(v);
        return;
    }

    // ---- layer1: h = relu(x @ W1^T + b1) -> Ht (fp16, unscaled) ----
    int wave = ((blockIdx.x - ABLK) * 256 + tid) >> 6;
    if (wave >= NTILES) return;
    int lane = tid & 63;
    int r16 = lane & 15, quad = lane >> 4;
    int base = wave * 16;

    bf16x8 a[4];
    const float* xr = x + (size_t)(base + r16) * 128 + quad * 8;
#pragma unroll
    for (int kb = 0; kb < 4; kb++) {
        float4 f0 = *(const float4*)(xr + kb * 32);
        float4 f1 = *(const float4*)(xr + kb * 32 + 4);
        bf16x8 v;
        v[0] = (short)f2bf(f0.x); v[1] = (short)f2bf(f0.y);
        v[2] = (short)f2bf(f0.z); v[3] = (short)f2bf(f0.w);
        v[4] = (short)f2bf(f1.x); v[5] = (short)f2bf(f1.y);
        v[6] = (short)f2bf(f1.z); v[7] = (short)f2bf(f1.w);
        a[kb] = v;
    }

#pragma unroll
    for (int jt = 0; jt < 4; jt++) {
        f32x4 acc = {0.f, 0.f, 0.f, 0.f};
        const float* wr = W1 + (size_t)(jt * 16 + r16) * 128 + quad * 8;
#pragma unroll
        for (int kb = 0; kb < 4; kb++) {
            float4 g0 = *(const float4*)(wr + kb * 32);
            float4 g1 = *(const float4*)(wr + kb * 32 + 4);
            bf16x8 b;
            b[0] = (short)f2bf(g0.x); b[1] = (short)f2bf(g0.y);
            b[2] = (short)f2bf(g0.z); b[3] = (short)f2bf(g0.w);
            b[4] = (short)f2bf(g1.x); b[5] = (short)f2bf(g1.y);
            b[6] = (short)f2bf(g1.z); b[7] = (short)f2bf(g1.w);
            acc = __builtin_amdgcn_mfma_f32_16x16x32_bf16(a[kb], b, acc, 0, 0, 0);
        }
        int col = jt * 16 + r16;
        float bias = b1[col];
#pragma unroll
        for (int r = 0; r < 4; r++) {
            int row = base + quad * 4 + r;
            float v = fmaxf(acc[r] + bias, 0.f);
            Ht[(size_t)row * 64 + col] = __float2half(v);
        }
    }
}

// ---------------------------------------------------------------------------
// PASS B (csr + scale FUSED): one block per bucket.
//  1) slot assignment via LDS atomics; scattered 2B stores confined to the
//     bucket's 32 KB srcAp region (L2-resident).
//  2) ZROW padding + cnt/isq/sdeg from the LDS degrees.
//  3) scale its 250 rows: As = Ht*isq (fp16), As8 = fp8 e4m3 gather copy.
__global__ __launch_bounds__(256) void csr_scale_k(const int* __restrict__ bucketCnt,
                                                   const unsigned int* __restrict__ bktArr,
                                                   const __half* __restrict__ Ht,
                                                   unsigned short* __restrict__ srcAp,
                                                   int* __restrict__ cnt,
                                                   __half* __restrict__ As,
                                                   unsigned char* __restrict__ As8,
                                                   float* __restrict__ isq,
                                                   float* __restrict__ sdeg) {
    __shared__ int lcnt[BKT_NODES];
    int b = blockIdx.x, tid = threadIdx.x;
    if (tid < BKT_NODES) lcnt[tid] = 0;
    __syncthreads();
    int n = min(bucketCnt[b], BKT_CAP);
    int rowbase = b * BKT_NODES;
    const unsigned int* arr = bktArr + (size_t)b * BKT_CAP;
    for (int i = tid; i < n; i += 256) {
        unsigned int u = arr[i];
        int dl = (int)(u >> 16);
        int pos = atomicAdd(&lcnt[dl], 1);
        if (pos < ROWCAP)
            srcAp[(size_t)(rowbase + dl) * ROWCAP + pos] = (unsigned short)(u & 0xFFFF);
    }
    __syncthreads();
    if (tid < BKT_NODES) {
        int deg = lcnt[tid];
        int cv = min(deg, ROWCAP);
        int cvr = (cv + 7) & ~7;
        for (int j = cv; j < cvr; j++)
            srcAp[(size_t)(rowbase + tid) * ROWCAP + j] = (unsigned short)ZROW;
        cnt[rowbase + tid] = deg;
        float dv = fmaxf((float)deg, 1.0f);
        isq[rowbase + tid] = rsqrtf(dv);
        sdeg[rowbase + tid] = sqrtf(dv);
    }
    __syncthreads();
    // scale: 16 threads per row, 16 rows per sweep
    int sl = tid & 15;
    for (int rr = tid >> 4; rr < BKT_NODES; rr += 16) {
        int row = rowbase + rr;
        float is = rsqrtf(fmaxf((float)lcnt[rr], 1.0f));
        uint2 rv = *((const uint2*)(Ht + (size_t)row * 64) + sl);   // 4 halves
        float2 fa = h2f2(rv.x), fb = h2f2(rv.y);
        float s0 = fa.x * is, s1 = fa.y * is, s2 = fb.x * is, s3 = fb.y * is;
        uint2 ov;
        ov.x = f22h2(s0, s1);
        ov.y = f22h2(s2, s3);
        *((uint2*)(As + (size_t)row * 64) + sl) = ov;
        unsigned int w = __builtin_amdgcn_cvt_pk_fp8_f32(s0, s1, 0, false);
        w = __builtin_amdgcn_cvt_pk_fp8_f32(s2, s3, w, true);
        ((unsigned int*)As8)[(size_t)row * 16 + sl] = w;            // 4 fp8 bytes
    }
}

// ---------------------------------------------------------------------------
// FUSED conv + dense, one block = 64 rows (4 MFMA tiles, wave-independent).
// conv: 16 rows x 4 feat-lanes, each lane gathers a 16B uint4 (quarter of the
//   64B fp8 row); one wave instruction covers 16 edges. Simple 8-chunk loop
//   (R9's 2-chunk deep unroll REVERTED: +5us vs best-measured config --
//   cold-gather exposure is issue/return-rate bound, not outstanding-count
//   bound; R1's MLP-doubling nulled for the same reason).
// dense: fp16 path; fp8 error enters ONLY through the conv half of concat.
__global__ __launch_bounds__(256) void conv_dense_k(const __half* __restrict__ hs,
                                                    const unsigned char* __restrict__ hs8,
                                                    const int* __restrict__ cnt,
                                                    const unsigned short* __restrict__ srcAp,
                                                    const float* __restrict__ isq,
                                                    const float* __restrict__ sdeg,
                                                    const unsigned short* __restrict__ wp,
                                                    const unsigned short* __restrict__ aap,
                                                    const unsigned short* __restrict__ abp,
                                                    __half* __restrict__ outs,
                                                    unsigned char* __restrict__ outs8,
                                                    float* __restrict__ outf,
                                                    int finalLayer) {
    __shared__ unsigned short clds[64][64];   // conv result (bf16), 8 KB
    int tid = threadIdx.x;
    int wv = tid >> 6;
    int lane = tid & 63;
    int t = blockIdx.x * 4 + wv;
    if (t >= NTILES) return;
    int base = t * 16;   // N_NODES % 16 == 0: all rows valid

    // ---- conv phase (no barrier: wave reads only its own clds quarter) ----
    {
        int r = lane >> 2, fl = lane & 3;      // 16 rows x 4 feat-lanes
        int row = base + r;
        int b = row * ROWCAP;
        int cv = min(cnt[row], ROWCAP);
        int cvr = (cv + 7) & ~7;               // slots [cv,cvr) = ZROW (zeros)
        f32x2 acc[8];
#pragma unroll
        for (int k = 0; k < 8; k++) acc[k] = (f32x2){0.f, 0.f};
        if (cvr) {
            u16x8 sv = __builtin_nontemporal_load((const u16x8*)(srcAp + b));
            for (int i = 0; i < cvr; i += 8) {
                u16x8 svn = sv;                // prefetch next slot vector
                if (i + 8 < cvr)
                    svn = __builtin_nontemporal_load((const u16x8*)(srcAp + b + i + 8));
                u32x4 rv[8];
#pragma unroll
                for (int u = 0; u < 8; u++)
                    rv[u] = *((const u32x4*)(hs8 + (size_t)(int)sv[u] * 64) + fl);
#pragma unroll
                for (int u = 0; u < 8; u++) {
                    acc[0] += __builtin_amdgcn_cvt_pk_f32_fp8(rv[u][0], false);
                    acc[1] += __builtin_amdgcn_cvt_pk_f32_fp8(rv[u][0], true);
                    acc[2] += __builtin_amdgcn_cvt_pk_f32_fp8(rv[u][1], false);
                    acc[3] += __builtin_amdgcn_cvt_pk_f32_fp8(rv[u][1], true);
                    acc[4] += __builtin_amdgcn_cvt_pk_f32_fp8(rv[u][2], false);
                    acc[5] += __builtin_amdgcn_cvt_pk_f32_fp8(rv[u][2], true);
                    acc[6] += __builtin_amdgcn_cvt_pk_f32_fp8(rv[u][3], false);
                    acc[7] += __builtin_amdgcn_cvt_pk_f32_fp8(rv[u][3], true);
                }
                sv = svn;
            }
        }
        float sc = isq[row];
        u16x8 o0, o1;
#pragma unroll
        for (int k = 0; k < 4; k++) {
            o0[2 * k]     = f2bf(acc[k][0] * sc);
            o0[2 * k + 1] = f2bf(acc[k][1] * sc);
            o1[2 * k]     = f2bf(acc[4 + k][0] * sc);
            o1[2 * k + 1] = f2bf(acc[4 + k][1] * sc);
        }
        // lane (r,fl) owns feats [fl*16, fl*16+16) of its row
        *(u16x8*)(&clds[wv * 16 + r][fl * 16]) = o0;
        *(u16x8*)(&clds[wv * 16 + r][fl * 16 + 8]) = o1;
    }

    // ---- dense phase ----
    int r16 = lane & 15, quad = lane >> 4;
    float rs = sdeg[base + r16];                 // h = hs * sqrt(deg), per A-row
    const u32x4* hp = (const u32x4*)(hs + (size_t)(base + r16) * 64);
    u32x4 raw0 = __builtin_nontemporal_load(hp + quad);      // feats quad*8 .. +8
    u32x4 raw1 = __builtin_nontemporal_load(hp + 4 + quad);  // feats 32+quad*8 .. +8
    bf16x8 ha0, ha1;
    {
        float2 f;
        f = h2f2(raw0[0]); ha0[0] = (short)f2bf(f.x * rs); ha0[1] = (short)f2bf(f.y * rs);
        f = h2f2(raw0[1]); ha0[2] = (short)f2bf(f.x * rs); ha0[3] = (short)f2bf(f.y * rs);
        f = h2f2(raw0[2]); ha0[4] = (short)f2bf(f.x * rs); ha0[5] = (short)f2bf(f.y * rs);
        f = h2f2(raw0[3]); ha0[6] = (short)f2bf(f.x * rs); ha0[7] = (short)f2bf(f.y * rs);
        f = h2f2(raw1[0]); ha1[0] = (short)f2bf(f.x * rs); ha1[1] = (short)f2bf(f.y * rs);
        f = h2f2(raw1[1]); ha1[2] = (short)f2bf(f.x * rs); ha1[3] = (short)f2bf(f.y * rs);
        f = h2f2(raw1[2]); ha1[4] = (short)f2bf(f.x * rs); ha1[5] = (short)f2bf(f.y * rs);
        f = h2f2(raw1[3]); ha1[6] = (short)f2bf(f.x * rs); ha1[7] = (short)f2bf(f.y * rs);
    }
    bf16x8 ca0 = *(const bf16x8*)(&clds[wv * 16 + r16][quad * 8]);
    bf16x8 ca1 = *(const bf16x8*)(&clds[wv * 16 + r16][32 + quad * 8]);

    float isq4[4];
    if (!finalLayer) {
#pragma unroll
        for (int r = 0; r < 4; r++) isq4[r] = isq[base + quad * 4 + r];
    }

#pragma unroll
    for (int jt = 0; jt < 4; jt++) {
        const unsigned short* wr = wp + (size_t)(jt * 16 + r16) * 128 + quad * 8;
        const unsigned short* ar = aap + (size_t)(jt * 16 + r16) * 64 + quad * 8;
        const unsigned short* br = abp + (size_t)(jt * 16 + r16) * 64 + quad * 8;
        f32x4 P = {0.f, 0.f, 0.f, 0.f};
        f32x4 Q = {0.f, 0.f, 0.f, 0.f};
        f32x4 R = {0.f, 0.f, 0.f, 0.f};
        P = __builtin_amdgcn_mfma_f32_16x16x32_bf16(ha0, *(const bf16x8*)(wr), P, 0, 0, 0);
        P = __builtin_amdgcn_mfma_f32_16x16x32_bf16(ha1, *(const bf16x8*)(wr + 32), P, 0, 0, 0);
        P = __builtin_amdgcn_mfma_f32_16x16x32_bf16(ca0, *(const bf16x8*)(wr + 64), P, 0, 0, 0);
        P = __builtin_amdgcn_mfma_f32_16x16x32_bf16(ca1, *(const bf16x8*)(wr + 96), P, 0, 0, 0);
        Q = __builtin_amdgcn_mfma_f32_16x16x32_bf16(ha0, *(const bf16x8*)(ar), Q, 0, 0, 0);
        Q = __builtin_amdgcn_mfma_f32_16x16x32_bf16(ha1, *(const bf16x8*)(ar + 32), Q, 0, 0, 0);
        R = __builtin_amdgcn_mfma_f32_16x16x32_bf16(ha0, *(const bf16x8*)(br), R, 0, 0, 0);
        R = __builtin_amdgcn_mfma_f32_16x16x32_bf16(ha1, *(const bf16x8*)(br + 32), R, 0, 0, 0);
        int col = jt * 16 + r16;
#pragma unroll
        for (int r = 0; r < 4; r++) {
            int row = base + quad * 4 + r;
            float v = fmaxf(P[r] + Q[r] * R[r], 0.f);
            if (finalLayer) {
                __builtin_nontemporal_store(v, &outf[(size_t)row * 64 + col]);
            } else {
                float vs = v * isq4[r];
                __half hv = __float2half(vs);
                __builtin_nontemporal_store(*(unsigned short*)&hv,
                                            (unsigned short*)outs + (size_t)row * 64 + col);
                unsigned int pb = __builtin_amdgcn_cvt_pk_fp8_f32(vs, vs, 0, false);
                __builtin_nontemporal_store((unsigned char)pb,
                                            &outs8[(size_t)row * 64 + col]);
            }
        }
    }
}

// ---------------------------------------------------------------------------
extern "C" void kernel_launch(void* const* d_in, const int* in_sizes, int n_in,
                              void* d_out, int out_size, void* d_ws, size_t ws_size,
                              hipStream_t stream) {
    const float* x = (const float*)d_in[0];
    const int* edges = (const int*)d_in[1];
    const float* W1 = (const float*)d_in[2];
    const float* b1 = (const float*)d_in[3];
    const float* W2 = (const float*)d_in[4];
    const float* A2a = (const float*)d_in[5];
    const float* A2b = (const float*)d_in[6];
    const float* W3 = (const float*)d_in[7];
    const float* A3a = (const float*)d_in[8];
    const float* A3b = (const float*)d_in[9];
    const float* W4 = (const float*)d_in[10];
    const float* A4a = (const float*)d_in[11];
    const float* A4b = (const float*)d_in[12];
    float* out = (float*)d_out;

    const int* src = edges;
    const int* dst = edges + N_EDGES;

    char* p = (char*)d_ws;
    auto alloc = [&](size_t bytes) {
        char* r = p;
        p += (bytes + 255) & ~(size_t)255;
        return r;
    };
    int* bucketCnt        = (int*)alloc(NBKT * 4);
    unsigned int* bktArr  = (unsigned int*)alloc((size_t)NBKT * BKT_CAP * 4);
    int* cnt              = (int*)alloc(N_NODES * 4);                 // full degree
    float* isq            = (float*)alloc(N_NODES * 4);
    float* sdeg           = (float*)alloc(N_NODES * 4);
    unsigned short* srcAp = (unsigned short*)alloc((size_t)N_NODES * ROWCAP * 2);
    unsigned short* wpAll = (unsigned short*)alloc(W_TOTAL * 2);
    __half* Ht            = (__half*)alloc((size_t)N_NODES * 64 * 2);
    __half* As            = (__half*)alloc((size_t)N_NODES * 64 * 2);
    __half* Bs            = (__half*)alloc((size_t)N_NODES * 64 * 2);
    unsigned char* As8    = (unsigned char*)alloc((size_t)(N_NODES + 1) * 64);  // +zero row
    unsigned char* Bs8    = (unsigned char*)alloc((size_t)(N_NODES + 1) * 64);

    const unsigned short* W2p  = wpAll + 8192;
    const unsigned short* A2ap = wpAll + 16384;
    const unsigned short* A2bp = wpAll + 20480;
    const unsigned short* W3p  = wpAll + 24576;
    const unsigned short* A3ap = wpAll + 32768;
    const unsigned short* A3bp = wpAll + 36864;
    const unsigned short* W4p  = wpAll + 40960;
    const unsigned short* A4ap = wpAll + 49152;
    const unsigned short* A4bp = wpAll + 53248;

    // single tiny memset (bucket counters); ZROW pad rows zeroed inside passA
    hipMemsetAsync(bucketCnt, 0, NBKT * 4, stream);

    // ---- pass A: bin edges || layer1 || weight pack + ZROW zeroing ----
    passA_kernel<<<ABLK + TB + WB2, 256, 0, stream>>>(
        x, src, dst, W1, b1, W2, A2a, A2b, W3, A3a, A3b, W4, A4a, A4b,
        bucketCnt, bktArr, wpAll, Ht, As8, Bs8);

    // ---- pass B: per-bucket CSR build + scale (fused) ----
    csr_scale_k<<<NBKT, 256, 0, stream>>>(bucketCnt, bktArr, Ht, srcAp, cnt,
                                          As, As8, isq, sdeg);

    // ---- layer 2: As -> Bs ----
    conv_dense_k<<<TB, 256, 0, stream>>>(As, As8, cnt, srcAp, isq, sdeg,
                                         W2p, A2ap, A2bp, Bs, Bs8, nullptr, 0);
    // ---- layer 3: Bs -> As ----
    conv_dense_k<<<TB, 256, 0, stream>>>(Bs, Bs8, cnt, srcAp, isq, sdeg,
                                         W3p, A3ap, A3bp, As, As8, nullptr, 0);
    // ---- layer 4: As -> out (fp32) ----
    conv_dense_k<<<TB, 256, 0, stream>>>(As, As8, cnt, srcAp, isq, sdeg,
                                         W4p, A4ap, A4bp, nullptr, nullptr, out, 1);
}

// Round 12
// 223.950 us; speedup vs baseline: 1.0704x; 1.0116x over previous
//
#include <hip/hip_runtime.h>
#include <hip/hip_bf16.h>
#include <hip/hip_fp16.h>

#define N_NODES 50000
#define N_EDGES 800000
#define NTILES 3125        // N_NODES / 16
#define W_TOTAL 57344      // packed bf16 weight elements (W1 slot unused)
#define WB2 192            // pack blocks (W2..A4b = 49152 elems)
#define TB 782             // layer1 MFMA blocks (4 waves each)
#define CB 1563            // conv_dense blocks (2 tiles / 32 rows each) -- R11
#define ROWCAP 64          // padded-CSR slots per node (deg mean 16, 12-sigma safe)
#define ZROW N_NODES       // index of the all-zero fp8 row used for slot padding

#define NBKT 200           // dst-range buckets
#define BKT_NODES 250      // nodes per bucket (200*250 = 50000)
#define BKT_CAP 4400       // edges per bucket capacity (mean 4000, +6.3 sigma)
#define ABLK 256           // bin blocks (phase A)
#define ACH ((N_EDGES + ABLK - 1) / ABLK)   // 3125 edges per bin block

typedef __attribute__((ext_vector_type(8))) short bf16x8;          // MFMA A/B frag
typedef __attribute__((ext_vector_type(4))) float f32x4;           // MFMA C/D frag
typedef __attribute__((ext_vector_type(2))) float f32x2;           // packed f32 pair
typedef __attribute__((ext_vector_type(8))) unsigned short u16x8;  // 16B load/store
typedef __attribute__((ext_vector_type(4))) unsigned int u32x4;    // 16B load (ext-vec for nt builtins)

__device__ inline unsigned short f2bf(float f) {  // round-to-nearest-even
    unsigned int x = __float_as_uint(f);
    unsigned int r = (x + 0x7FFF + ((x >> 16) & 1)) >> 16;
    return (unsigned short)r;
}
__device__ inline float2 h2f2(unsigned int u) {   // packed half2 -> float2
    __half2 h = *(__half2*)&u;
    return make_float2(__low2float(h), __high2float(h));
}
__device__ inline unsigned int f22h2(float a, float b) {  // 2 floats -> packed half2
    __half2 h = __floats2half2_rn(a, b);
    return *(unsigned int*)&h;
}

// ---------------------------------------------------------------------------
// PASS A (one launch, three independent block roles):
//  [0, ABLK)        : edge BINNING by dst-range (LDS histogram + one global
//                     atomic per (block,bucket), packed (dl<<16|src) run writes).
//  [ABLK, +TB)      : layer1 MFMA -> UNSCALED h (fp16) in Ht.
//  [ABLK+TB, end)   : bf16-pack W2..A4b into wpAll[8192..]; first pack block
//                     also zeroes the As8/Bs8 ZROW pad rows (replaces two
//                     64B memset launches -- consumed only after csr_scale).
__global__ __launch_bounds__(256) void passA_kernel(
    const float* __restrict__ x, const int* __restrict__ src, const int* __restrict__ dst,
    const float* __restrict__ W1, const float* __restrict__ b1,
    const float* W2, const float* A2a, const float* A2b,
    const float* W3, const float* A3a, const float* A3b,
    const float* W4, const float* A4a, const float* A4b,
    int* __restrict__ bucketCnt, unsigned int* __restrict__ bktArr,
    unsigned short* __restrict__ wp, __half* __restrict__ Ht,
    unsigned char* __restrict__ As8, unsigned char* __restrict__ Bs8) {
    int tid = threadIdx.x;

    if (blockIdx.x < ABLK) {                      // ---- bin edges ----
        __shared__ int hist[NBKT];
        __shared__ int gbase[NBKT];
        __shared__ int hoff[NBKT];
        if (tid < NBKT) { hist[tid] = 0; hoff[tid] = 0; }
        __syncthreads();
        int e0 = blockIdx.x * ACH;
        int e1 = min(e0 + ACH, N_EDGES);
        for (int e = e0 + tid; e < e1; e += 256)
            atomicAdd(&hist[dst[e] / BKT_NODES], 1);
        __syncthreads();
        if (tid < NBKT) {
            int h = hist[tid];
            gbase[tid] = h ? atomicAdd(&bucketCnt[tid], h) : 0;
        }
        __syncthreads();
        for (int e = e0 + tid; e < e1; e += 256) {
            int d = dst[e];
            int b = d / BKT_NODES;
            int pos = gbase[b] + atomicAdd(&hoff[b], 1);
            if (pos < BKT_CAP)
                bktArr[(size_t)b * BKT_CAP + pos] =
                    ((unsigned int)(d - b * BKT_NODES) << 16) | (unsigned int)src[e];
        }
        return;
    }
    if (blockIdx.x >= ABLK + TB) {                // ---- pack W2..A4b ----
        if (blockIdx.x == ABLK + TB) {            // zero the ZROW pad rows
            if (tid < 16)      ((unsigned int*)(As8 + (size_t)ZROW * 64))[tid] = 0u;
            else if (tid < 32) ((unsigned int*)(Bs8 + (size_t)ZROW * 64))[tid - 16] = 0u;
        }
        int i = 8192 + (blockIdx.x - ABLK - TB) * 256 + tid;
        if (i >= W_TOTAL) return;
        float v;
        if (i < 16384)      v = W2[i - 8192];
        else if (i < 20480) v = A2a[i - 16384];
        else if (i < 24576) v = A2b[i - 20480];
        else if (i < 32768) v = W3[i - 24576];
        else if (i < 36864) v = A3a[i - 32768];
        else if (i < 40960) v = A3b[i - 36864];
        else if (i < 49152) v = W4[i - 40960];
        else if (i < 53248) v = A4a[i - 49152];
        else                v = A4b[i - 53248];
        wp[i] = f2bf(v);
        return;
    }

    // ---- layer1: h = relu(x @ W1^T + b1) -> Ht (fp16, unscaled) ----
    int wave = ((blockIdx.x - ABLK) * 256 + tid) >> 6;
    if (wave >= NTILES) return;
    int lane = tid & 63;
    int r16 = lane & 15, quad = lane >> 4;
    int base = wave * 16;

    bf16x8 a[4];
    const float* xr = x + (size_t)(base + r16) * 128 + quad * 8;
#pragma unroll
    for (int kb = 0; kb < 4; kb++) {
        float4 f0 = *(const float4*)(xr + kb * 32);
        float4 f1 = *(const float4*)(xr + kb * 32 + 4);
        bf16x8 v;
        v[0] = (short)f2bf(f0.x); v[1] = (short)f2bf(f0.y);
        v[2] = (short)f2bf(f0.z); v[3] = (short)f2bf(f0.w);
        v[4] = (short)f2bf(f1.x); v[5] = (short)f2bf(f1.y);
        v[6] = (short)f2bf(f1.z); v[7] = (short)f2bf(f1.w);
        a[kb] = v;
    }

#pragma unroll
    for (int jt = 0; jt < 4; jt++) {
        f32x4 acc = {0.f, 0.f, 0.f, 0.f};
        const float* wr = W1 + (size_t)(jt * 16 + r16) * 128 + quad * 8;
#pragma unroll
        for (int kb = 0; kb < 4; kb++) {
            float4 g0 = *(const float4*)(wr + kb * 32);
            float4 g1 = *(const float4*)(wr + kb * 32 + 4);
            bf16x8 b;
            b[0] = (short)f2bf(g0.x); b[1] = (short)f2bf(g0.y);
            b[2] = (short)f2bf(g0.z); b[3] = (short)f2bf(g0.w);
            b[4] = (short)f2bf(g1.x); b[5] = (short)f2bf(g1.y);
            b[6] = (short)f2bf(g1.z); b[7] = (short)f2bf(g1.w);
            acc = __builtin_amdgcn_mfma_f32_16x16x32_bf16(a[kb], b, acc, 0, 0, 0);
        }
        int col = jt * 16 + r16;
        float bias = b1[col];
#pragma unroll
        for (int r = 0; r < 4; r++) {
            int row = base + quad * 4 + r;
            float v = fmaxf(acc[r] + bias, 0.f);
            Ht[(size_t)row * 64 + col] = __float2half(v);
        }
    }
}

// ---------------------------------------------------------------------------
// PASS B (csr + scale FUSED): one block per bucket.
//  1) slot assignment via LDS atomics; scattered 2B stores confined to the
//     bucket's 32 KB srcAp region (L2-resident).
//  2) ZROW padding + cnt/isq/sdeg from the LDS degrees.
//  3) scale its 250 rows: As = Ht*isq (fp16), As8 = fp8 e4m3 gather copy.
__global__ __launch_bounds__(256) void csr_scale_k(const int* __restrict__ bucketCnt,
                                                   const unsigned int* __restrict__ bktArr,
                                                   const __half* __restrict__ Ht,
                                                   unsigned short* __restrict__ srcAp,
                                                   int* __restrict__ cnt,
                                                   __half* __restrict__ As,
                                                   unsigned char* __restrict__ As8,
                                                   float* __restrict__ isq,
                                                   float* __restrict__ sdeg) {
    __shared__ int lcnt[BKT_NODES];
    int b = blockIdx.x, tid = threadIdx.x;
    if (tid < BKT_NODES) lcnt[tid] = 0;
    __syncthreads();
    int n = min(bucketCnt[b], BKT_CAP);
    int rowbase = b * BKT_NODES;
    const unsigned int* arr = bktArr + (size_t)b * BKT_CAP;
    for (int i = tid; i < n; i += 256) {
        unsigned int u = arr[i];
        int dl = (int)(u >> 16);
        int pos = atomicAdd(&lcnt[dl], 1);
        if (pos < ROWCAP)
            srcAp[(size_t)(rowbase + dl) * ROWCAP + pos] = (unsigned short)(u & 0xFFFF);
    }
    __syncthreads();
    if (tid < BKT_NODES) {
        int deg = lcnt[tid];
        int cv = min(deg, ROWCAP);
        int cvr = (cv + 7) & ~7;
        for (int j = cv; j < cvr; j++)
            srcAp[(size_t)(rowbase + tid) * ROWCAP + j] = (unsigned short)ZROW;
        cnt[rowbase + tid] = deg;
        float dv = fmaxf((float)deg, 1.0f);
        isq[rowbase + tid] = rsqrtf(dv);
        sdeg[rowbase + tid] = sqrtf(dv);
    }
    __syncthreads();
    // scale: 16 threads per row, 16 rows per sweep
    int sl = tid & 15;
    for (int rr = tid >> 4; rr < BKT_NODES; rr += 16) {
        int row = rowbase + rr;
        float is = rsqrtf(fmaxf((float)lcnt[rr], 1.0f));
        uint2 rv = *((const uint2*)(Ht + (size_t)row * 64) + sl);   // 4 halves
        float2 fa = h2f2(rv.x), fb = h2f2(rv.y);
        float s0 = fa.x * is, s1 = fa.y * is, s2 = fb.x * is, s3 = fb.y * is;
        uint2 ov;
        ov.x = f22h2(s0, s1);
        ov.y = f22h2(s2, s3);
        *((uint2*)(As + (size_t)row * 64) + sl) = ov;
        unsigned int w = __builtin_amdgcn_cvt_pk_fp8_f32(s0, s1, 0, false);
        w = __builtin_amdgcn_cvt_pk_fp8_f32(s2, s3, w, true);
        ((unsigned int*)As8)[(size_t)row * 16 + sl] = w;            // 4 fp8 bytes
    }
}

// ---------------------------------------------------------------------------
// FUSED conv + dense (R11 -- occupancy-doubled decomposition).
// The conv phase sits at 12.2 waves/CU (38% of capacity), capped by the work
// decomposition (1 wave per 16-row tile), not by VGPR/LDS. Per-wave latency
// levers (MLP count R1, unroll depth R9) both nulled; TLP is the untested
// axis. New shape: block = 32 rows (2 tiles), conv = 32 rows x 8 feat-lanes
// (uint2 = 8 fp8 feats/lane, same per-lane serial chain), grid 782 -> 1563
// blocks => ~24 waves/CU during conv (2x). Dense: after __syncthreads(),
// waves 0-1 run the two 16x16 MFMA tiles; waves 2-3 exit (dense is the
// cheap part). LDS 4 KB.
__global__ __launch_bounds__(256) void conv_dense_k(const __half* __restrict__ hs,
                                                    const unsigned char* __restrict__ hs8,
                                                    const int* __restrict__ cnt,
                                                    const unsigned short* __restrict__ srcAp,
                                                    const float* __restrict__ isq,
                                                    const float* __restrict__ sdeg,
                                                    const unsigned short* __restrict__ wp,
                                                    const unsigned short* __restrict__ aap,
                                                    const unsigned short* __restrict__ abp,
                                                    __half* __restrict__ outs,
                                                    unsigned char* __restrict__ outs8,
                                                    float* __restrict__ outf,
                                                    int finalLayer) {
    __shared__ unsigned short clds[32][64];   // conv result (bf16), 4 KB
    int tid = threadIdx.x;
    int t0 = blockIdx.x * 2;                  // this block's first tile
    int rowbase = t0 * 16;

    // ---- conv phase: 32 rows x 8 feat-lanes (8 fp8 feats = uint2 per lane) ----
    {
        int lrow = tid >> 3, fl = tid & 7;
        int row = rowbase + lrow;
        if (row < N_NODES) {
            int b = row * ROWCAP;
            int cv = min(cnt[row], ROWCAP);
            int cvr = (cv + 7) & ~7;           // slots [cv,cvr) = ZROW (zeros)
            f32x2 acc[4];
#pragma unroll
            for (int k = 0; k < 4; k++) acc[k] = (f32x2){0.f, 0.f};
            if (cvr) {
                u16x8 sv = __builtin_nontemporal_load((const u16x8*)(srcAp + b));
                for (int i = 0; i < cvr; i += 8) {
                    u16x8 svn = sv;            // prefetch next slot vector
                    if (i + 8 < cvr)
                        svn = __builtin_nontemporal_load((const u16x8*)(srcAp + b + i + 8));
                    uint2 rv[8];
#pragma unroll
                    for (int u = 0; u < 8; u++)
                        rv[u] = *((const uint2*)(hs8 + (size_t)(int)sv[u] * 64) + fl);
#pragma unroll
                    for (int u = 0; u < 8; u++) {
                        acc[0] += __builtin_amdgcn_cvt_pk_f32_fp8(rv[u].x, false);
                        acc[1] += __builtin_amdgcn_cvt_pk_f32_fp8(rv[u].x, true);
                        acc[2] += __builtin_amdgcn_cvt_pk_f32_fp8(rv[u].y, false);
                        acc[3] += __builtin_amdgcn_cvt_pk_f32_fp8(rv[u].y, true);
                    }
                    sv = svn;
                }
            }
            float sc = isq[row];
            u16x8 o;
#pragma unroll
            for (int k = 0; k < 4; k++) {
                o[2 * k]     = f2bf(acc[k][0] * sc);
                o[2 * k + 1] = f2bf(acc[k][1] * sc);
            }
            // lane (lrow, fl) owns feats [fl*8, fl*8+8) of its row
            *(u16x8*)(&clds[lrow][fl * 8]) = o;
        }
    }
    __syncthreads();   // conv rows span waves; dense reads across them

    // ---- dense phase: waves 0,1 -> tiles t0, t0+1 ----
    int wv = tid >> 6;
    if (wv >= 2) return;
    int t = t0 + wv;
    if (t >= NTILES) return;
    int base = t * 16;
    int lane = tid & 63;
    int r16 = lane & 15, quad = lane >> 4;
    float rs = sdeg[base + r16];                 // h = hs * sqrt(deg), per A-row
    const u32x4* hp = (const u32x4*)(hs + (size_t)(base + r16) * 64);
    u32x4 raw0 = __builtin_nontemporal_load(hp + quad);      // feats quad*8 .. +8
    u32x4 raw1 = __builtin_nontemporal_load(hp + 4 + quad);  // feats 32+quad*8 .. +8
    bf16x8 ha0, ha1;
    {
        float2 f;
        f = h2f2(raw0[0]); ha0[0] = (short)f2bf(f.x * rs); ha0[1] = (short)f2bf(f.y * rs);
        f = h2f2(raw0[1]); ha0[2] = (short)f2bf(f.x * rs); ha0[3] = (short)f2bf(f.y * rs);
        f = h2f2(raw0[2]); ha0[4] = (short)f2bf(f.x * rs); ha0[5] = (short)f2bf(f.y * rs);
        f = h2f2(raw0[3]); ha0[6] = (short)f2bf(f.x * rs); ha0[7] = (short)f2bf(f.y * rs);
        f = h2f2(raw1[0]); ha1[0] = (short)f2bf(f.x * rs); ha1[1] = (short)f2bf(f.y * rs);
        f = h2f2(raw1[1]); ha1[2] = (short)f2bf(f.x * rs); ha1[3] = (short)f2bf(f.y * rs);
        f = h2f2(raw1[2]); ha1[4] = (short)f2bf(f.x * rs); ha1[5] = (short)f2bf(f.y * rs);
        f = h2f2(raw1[3]); ha1[6] = (short)f2bf(f.x * rs); ha1[7] = (short)f2bf(f.y * rs);
    }
    bf16x8 ca0 = *(const bf16x8*)(&clds[wv * 16 + r16][quad * 8]);
    bf16x8 ca1 = *(const bf16x8*)(&clds[wv * 16 + r16][32 + quad * 8]);

    float isq4[4];
    if (!finalLayer) {
#pragma unroll
        for (int r = 0; r < 4; r++) isq4[r] = isq[base + quad * 4 + r];
    }

#pragma unroll
    for (int jt = 0; jt < 4; jt++) {
        const unsigned short* wr = wp + (size_t)(jt * 16 + r16) * 128 + quad * 8;
        const unsigned short* ar = aap + (size_t)(jt * 16 + r16) * 64 + quad * 8;
        const unsigned short* br = abp + (size_t)(jt * 16 + r16) * 64 + quad * 8;
        f32x4 P = {0.f, 0.f, 0.f, 0.f};
        f32x4 Q = {0.f, 0.f, 0.f, 0.f};
        f32x4 R = {0.f, 0.f, 0.f, 0.f};
        P = __builtin_amdgcn_mfma_f32_16x16x32_bf16(ha0, *(const bf16x8*)(wr), P, 0, 0, 0);
        P = __builtin_amdgcn_mfma_f32_16x16x32_bf16(ha1, *(const bf16x8*)(wr + 32), P, 0, 0, 0);
        P = __builtin_amdgcn_mfma_f32_16x16x32_bf16(ca0, *(const bf16x8*)(wr + 64), P, 0, 0, 0);
        P = __builtin_amdgcn_mfma_f32_16x16x32_bf16(ca1, *(const bf16x8*)(wr + 96), P, 0, 0, 0);
        Q = __builtin_amdgcn_mfma_f32_16x16x32_bf16(ha0, *(const bf16x8*)(ar), Q, 0, 0, 0);
        Q = __builtin_amdgcn_mfma_f32_16x16x32_bf16(ha1, *(const bf16x8*)(ar + 32), Q, 0, 0, 0);
        R = __builtin_amdgcn_mfma_f32_16x16x32_bf16(ha0, *(const bf16x8*)(br), R, 0, 0, 0);
        R = __builtin_amdgcn_mfma_f32_16x16x32_bf16(ha1, *(const bf16x8*)(br + 32), R, 0, 0, 0);
        int col = jt * 16 + r16;
#pragma unroll
        for (int r = 0; r < 4; r++) {
            int row = base + quad * 4 + r;
            float v = fmaxf(P[r] + Q[r] * R[r], 0.f);
            if (finalLayer) {
                __builtin_nontemporal_store(v, &outf[(size_t)row * 64 + col]);
            } else {
                float vs = v * isq4[r];
                __half hv = __float2half(vs);
                __builtin_nontemporal_store(*(unsigned short*)&hv,
                                            (unsigned short*)outs + (size_t)row * 64 + col);
                unsigned int pb = __builtin_amdgcn_cvt_pk_fp8_f32(vs, vs, 0, false);
                __builtin_nontemporal_store((unsigned char)pb,
                                            &outs8[(size_t)row * 64 + col]);
            }
        }
    }
}

// ---------------------------------------------------------------------------
extern "C" void kernel_launch(void* const* d_in, const int* in_sizes, int n_in,
                              void* d_out, int out_size, void* d_ws, size_t ws_size,
                              hipStream_t stream) {
    const float* x = (const float*)d_in[0];
    const int* edges = (const int*)d_in[1];
    const float* W1 = (const float*)d_in[2];
    const float* b1 = (const float*)d_in[3];
    const float* W2 = (const float*)d_in[4];
    const float* A2a = (const float*)d_in[5];
    const float* A2b = (const float*)d_in[6];
    const float* W3 = (const float*)d_in[7];
    const float* A3a = (const float*)d_in[8];
    const float* A3b = (const float*)d_in[9];
    const float* W4 = (const float*)d_in[10];
    const float* A4a = (const float*)d_in[11];
    const float* A4b = (const float*)d_in[12];
    float* out = (float*)d_out;

    const int* src = edges;
    const int* dst = edges + N_EDGES;

    char* p = (char*)d_ws;
    auto alloc = [&](size_t bytes) {
        char* r = p;
        p += (bytes + 255) & ~(size_t)255;
        return r;
    };
    int* bucketCnt        = (int*)alloc(NBKT * 4);
    unsigned int* bktArr  = (unsigned int*)alloc((size_t)NBKT * BKT_CAP * 4);
    int* cnt              = (int*)alloc(N_NODES * 4);                 // full degree
    float* isq            = (float*)alloc(N_NODES * 4);
    float* sdeg           = (float*)alloc(N_NODES * 4);
    unsigned short* srcAp = (unsigned short*)alloc((size_t)N_NODES * ROWCAP * 2);
    unsigned short* wpAll = (unsigned short*)alloc(W_TOTAL * 2);
    __half* Ht            = (__half*)alloc((size_t)N_NODES * 64 * 2);
    __half* As            = (__half*)alloc((size_t)N_NODES * 64 * 2);
    __half* Bs            = (__half*)alloc((size_t)N_NODES * 64 * 2);
    unsigned char* As8    = (unsigned char*)alloc((size_t)(N_NODES + 1) * 64);  // +zero row
    unsigned char* Bs8    = (unsigned char*)alloc((size_t)(N_NODES + 1) * 64);

    const unsigned short* W2p  = wpAll + 8192;
    const unsigned short* A2ap = wpAll + 16384;
    const unsigned short* A2bp = wpAll + 20480;
    const unsigned short* W3p  = wpAll + 24576;
    const unsigned short* A3ap = wpAll + 32768;
    const unsigned short* A3bp = wpAll + 36864;
    const unsigned short* W4p  = wpAll + 40960;
    const unsigned short* A4ap = wpAll + 49152;
    const unsigned short* A4bp = wpAll + 53248;

    // single tiny memset (bucket counters); ZROW pad rows zeroed inside passA
    hipMemsetAsync(bucketCnt, 0, NBKT * 4, stream);

    // ---- pass A: bin edges || layer1 || weight pack + ZROW zeroing ----
    passA_kernel<<<ABLK + TB + WB2, 256, 0, stream>>>(
        x, src, dst, W1, b1, W2, A2a, A2b, W3, A3a, A3b, W4, A4a, A4b,
        bucketCnt, bktArr, wpAll, Ht, As8, Bs8);

    // ---- pass B: per-bucket CSR build + scale (fused) ----
    csr_scale_k<<<NBKT, 256, 0, stream>>>(bucketCnt, bktArr, Ht, srcAp, cnt,
                                          As, As8, isq, sdeg);

    // ---- layer 2: As -> Bs ----
    conv_dense_k<<<CB, 256, 0, stream>>>(As, As8, cnt, srcAp, isq, sdeg,
                                         W2p, A2ap, A2bp, Bs, Bs8, nullptr, 0);
    // ---- layer 3: Bs -> As ----
    conv_dense_k<<<CB, 256, 0, stream>>>(Bs, Bs8, cnt, srcAp, isq, sdeg,
                                         W3p, A3ap, A3bp, As, As8, nullptr, 0);
    // ---- layer 4: As -> out (fp32) ----
    conv_dense_k<<<CB, 256, 0, stream>>>(As, As8, cnt, srcAp, isq, sdeg,
                                         W4p, A4ap, A4bp, nullptr, nullptr, out, 1);
}